// Round 10
// baseline (570.535 us; speedup 1.0000x reference)
//
#include <hip/hip_runtime.h>
#include <hip/hip_bf16.h>
#include <math.h>

#define BT 2
#define SEQ 2048
#define DIM 1024
#define NH 16
#define HD 64
#define NTOK (BT*SEQ)          // 4096

typedef __attribute__((ext_vector_type(4))) float floatx4;
typedef __attribute__((ext_vector_type(8))) short shortx8;   // 8 bf16 = 4 VGPRs (MFMA frag)
typedef __attribute__((ext_vector_type(4))) short shortx4;

// async global->LDS, 16B per lane; dest is wave-uniform base + lane*16
#define GLL16(gp, lp) __builtin_amdgcn_global_load_lds( \
    (const __attribute__((address_space(1))) unsigned int*)(const void*)(gp), \
    (__attribute__((address_space(3))) unsigned int*)(void*)(lp), 16, 0, 0)

// counted vmcnt wait: loads beyond the N newest must retire; N never 0 mid-loop
template<int N> __device__ __forceinline__ void waitvm() {
    if constexpr (N == 0) asm volatile("s_waitcnt vmcnt(0)" ::: "memory");
    else if constexpr (N == 3) asm volatile("s_waitcnt vmcnt(3)" ::: "memory");
    else if constexpr (N == 4) asm volatile("s_waitcnt vmcnt(4)" ::: "memory");
}
// barrier with lgkmcnt(0) drain only (ds_reads complete; vmcnt queue preserved)
__device__ __forceinline__ void barrier_lgkm() {
    asm volatile("s_waitcnt lgkmcnt(0)" ::: "memory");
    __builtin_amdgcn_s_barrier();
    asm volatile("" ::: "memory");
}

__device__ __forceinline__ float bf2f(unsigned short u) {
    unsigned int x = ((unsigned int)u) << 16;
    return __builtin_bit_cast(float, x);
}
__device__ __forceinline__ unsigned short f2bf(float f) {
    unsigned int x = __builtin_bit_cast(unsigned int, f);
    unsigned int lsb = (x >> 16) & 1u;
    x += 0x7fffu + lsb;
    return (unsigned short)(x >> 16);
}
// dual-dtype input read: isbf=1 -> bf16, else fp32 (validated: inputs are fp32)
__device__ __forceinline__ float ldin_f(const void* p, size_t i, int isbf) {
    return isbf ? bf2f(((const unsigned short*)p)[i]) : ((const float*)p)[i];
}

// ---------------- input dtype detection (validated R1->R2) ----------------
__global__ void detect_kernel(const unsigned short* __restrict__ x, int* __restrict__ flag) {
    __shared__ int cnt;
    if (threadIdx.x == 0) cnt = 0;
    __syncthreads();
    unsigned short u = x[(size_t)threadIdx.x * 2];
    int e = (u >> 7) & 0xFF;
    if (e >= 100 && e <= 140) atomicAdd(&cnt, 1);
    __syncthreads();
    if (threadIdx.x == 0) *flag = (cnt >= 192) ? 1 : 0;
}

// ---------------- transpose (any float dtype -> bf16) ----------------
__global__ void transpose_any(const void* __restrict__ in,
                              unsigned short* __restrict__ out, int R, int C,
                              const int* __restrict__ flagp) {
    int isbf = *flagp;
    __shared__ unsigned short tile[32][33];
    int c0 = blockIdx.x * 32, r0 = blockIdx.y * 32;
    int tx = threadIdx.x, ty = threadIdx.y;
#pragma unroll
    for (int i = 0; i < 4; i++) {
        size_t idx = (size_t)(r0 + ty + i * 8) * C + c0 + tx;
        tile[ty + i * 8][tx] = isbf ? ((const unsigned short*)in)[idx]
                                    : f2bf(((const float*)in)[idx]);
    }
    __syncthreads();
#pragma unroll
    for (int i = 0; i < 4; i++)
        out[(size_t)(c0 + ty + i * 8) * R + r0 + tx] = tile[tx][ty + i * 8];
}

// ---------------- Householder Q (64x64 fp32), register-resident columns ----------
__global__ __launch_bounds__(64) void householder_kernel(const void* __restrict__ vs,
                                                         float* __restrict__ Qg,
                                                         const int* __restrict__ flagp) {
    int isbf = *flagp;
    __shared__ float vsh[64];
    int j = threadIdx.x;
    float Qc[64];
#pragma unroll
    for (int i = 0; i < 64; i++) Qc[i] = (i == j) ? 1.f : 0.f;
    for (int r = 0; r < 32; r++) {
        vsh[j] = ldin_f(vs, r * 64 + j, isbf);
        __syncthreads();
        float va[64];
#pragma unroll
        for (int i = 0; i < 64; i++) va[i] = vsh[i];
        float vn0 = 0.f, vn1 = 0.f, vn2 = 0.f, vn3 = 0.f;
        float t0 = 0.f, t1 = 0.f, t2 = 0.f, t3 = 0.f;
#pragma unroll
        for (int i = 0; i < 16; i++) {
            vn0 += va[4 * i + 0] * va[4 * i + 0];
            vn1 += va[4 * i + 1] * va[4 * i + 1];
            vn2 += va[4 * i + 2] * va[4 * i + 2];
            vn3 += va[4 * i + 3] * va[4 * i + 3];
            t0 += va[4 * i + 0] * Qc[4 * i + 0];
            t1 += va[4 * i + 1] * Qc[4 * i + 1];
            t2 += va[4 * i + 2] * Qc[4 * i + 2];
            t3 += va[4 * i + 3] * Qc[4 * i + 3];
        }
        float vn = (vn0 + vn1) + (vn2 + vn3) + 1e-8f;
        float t = (t0 + t1) + (t2 + t3);
        float c = (2.f / vn) * t;
#pragma unroll
        for (int i = 0; i < 64; i++) Qc[i] -= c * va[i];
        __syncthreads();
    }
#pragma unroll
    for (int i = 0; i < 64; i++) Qg[i * 64 + j] = Qc[i];
}

// ---------------- pre-rotate q,k head-blocks of wqkvT by Q: W'[hb] = Q @ W[hb] ----
__global__ __launch_bounds__(256) void rotate_wqkv(unsigned short* __restrict__ wT,
                                                   const float* __restrict__ Qg) {
    __shared__ float Qs[64][64];
    __shared__ unsigned short tile[64][128];
    int bid = blockIdx.x;
    int row0 = (bid >> 3) * 64;      // head-block base row (0..2047)
    int col0 = (bid & 7) * 128;      // column chunk
    int t = threadIdx.x;
#pragma unroll
    for (int i = 0; i < 16; i++) {
        int idx = i * 256 + t;
        Qs[idx >> 6][idx & 63] = Qg[idx];
    }
#pragma unroll
    for (int i = 0; i < 8; i++) {
        int e = i * 256 + t;
        int r = e >> 5, cg = (e & 31) * 4;
        *(shortx4*)&tile[r][cg] = *(const shortx4*)&wT[(size_t)(row0 + r) * 1024 + col0 + cg];
    }
    __syncthreads();
    int ib = t >> 5;                 // 0..7
    int c = (t & 31) * 4;
    float acc[8][4];
#pragma unroll
    for (int rr = 0; rr < 8; rr++)
#pragma unroll
        for (int cx = 0; cx < 4; cx++) acc[rr][cx] = 0.f;
    for (int j = 0; j < 64; j++) {
        float t0 = bf2f(tile[j][c]);
        float t1 = bf2f(tile[j][c + 1]);
        float t2 = bf2f(tile[j][c + 2]);
        float t3 = bf2f(tile[j][c + 3]);
#pragma unroll
        for (int rr = 0; rr < 8; rr++) {
            float qv = Qs[rr * 8 + ib][j];
            acc[rr][0] += qv * t0;
            acc[rr][1] += qv * t1;
            acc[rr][2] += qv * t2;
            acc[rr][3] += qv * t3;
        }
    }
#pragma unroll
    for (int rr = 0; rr < 8; rr++) {
        int i = rr * 8 + ib;
        shortx4 o4;
#pragma unroll
        for (int cx = 0; cx < 4; cx++) o4[cx] = (short)f2bf(acc[rr][cx]);
        *(shortx4*)&wT[(size_t)(row0 + i) * 1024 + col0 + c] = o4;
    }
}

// ---------------- rope cos/sin table [2048][32] interleaved (cos,sin) ----------
__global__ void rope_table(float* __restrict__ tab) {
    int idx = blockIdx.x * 256 + threadIdx.x;    // s*32 + fi
    int s = idx >> 5, fi = idx & 31;
    float invf = __expf(-(float)fi * (9.210340371976184f / 32.f));  // 10000^(-fi/32)
    float ang = (float)s * invf;
    tab[2 * idx]     = cosf(ang);
    tab[2 * idx + 1] = sinf(ang);
}

// ---------------- rmsnorm over D=1024, LDS tree reduction ----------------
__global__ __launch_bounds__(256) void rmsnorm2(const void* __restrict__ x,
                                                unsigned short* __restrict__ h,
                                                const int* __restrict__ flagp) {
    int isbf = flagp ? *flagp : 1;
    __shared__ float red[256];
    int row = blockIdx.x, t = threadIdx.x;
    size_t base = (size_t)row * DIM;
    float v[4];
    float ss = 0.f;
#pragma unroll
    for (int i = 0; i < 4; i++) {
        v[i] = ldin_f(x, base + t + 256 * i, isbf);
        ss += v[i] * v[i];
    }
    red[t] = ss;
    __syncthreads();
    for (int s = 128; s > 0; s >>= 1) {
        if (t < s) red[t] += red[t + s];
        __syncthreads();
    }
    float rs = rsqrtf(red[0] * (1.f / 1024.f) + 1e-6f);
#pragma unroll
    for (int i = 0; i < 4; i++) h[base + t + 256 * i] = f2bf(v[i] * rs);
}

// ---------------- MFMA GEMM: 3-buffer 2-deep counted-vmcnt pipeline ----------
// One barrier (lgkmcnt(0)-only) per K-step; vmcnt(NLD) waits only the tile
// about to be consumed; 2 tiles stay in flight across barriers (AITER pattern).
// MODE: 0=bf16 store, 1=f32+resid, 2=gated combine x1=xin+resid*sigmoid(val+bias).
template<int BN, int MODE>
__global__ __launch_bounds__(256) void gemm_bt(const unsigned short* __restrict__ A,
                                               const unsigned short* __restrict__ Bt,
                                               void* __restrict__ C,
                                               const void* __restrict__ bias,
                                               const unsigned short* __restrict__ resid,
                                               const void* __restrict__ xin,
                                               const int* __restrict__ flagp,
                                               int M, int N, int K) {
    constexpr int NJ = BN / 32;              // col sub-tiles per wave (4 or 2)
    constexpr int NLD = (BN == 128) ? 4 : 3; // global_load_lds per thread per K-step
    __shared__ __align__(16) unsigned short As[3][128][32];
    __shared__ __align__(16) unsigned short Bs[3][BN][32];
    int isbf = flagp ? *flagp : 1;
    // XCD-chunked swizzle (grids are %8==0)
    int tile = (blockIdx.x & 7) * (gridDim.x >> 3) + (blockIdx.x >> 3);
    int nbn = N / BN;
    int m0 = (tile / nbn) * 128;             // m-major: contiguous tiles share A-panel
    int n0 = (tile % nbn) * BN;
    int t = threadIdx.x;
    int lane = t & 63;
    int w = t >> 6;
    int wr = (w >> 1) * 64;
    int wc = (w & 1) * (16 * NJ);
    int lr = lane & 15;
    int kg = lane >> 4;

    floatx4 acc[4][NJ];
#pragma unroll
    for (int i = 0; i < 4; i++)
#pragma unroll
        for (int j = 0; j < NJ; j++) acc[i][j] = (floatx4){0.f, 0.f, 0.f, 0.f};

    int srow = w * 16 + (lane >> 2);        // row within tile
    int skseg = (lane & 3) * 8;             // k-offset in shorts
    const unsigned short* aP = A + (size_t)(m0 + srow) * K + skseg;
    const unsigned short* bP = Bt + (size_t)(n0 + srow) * K + skseg;
    size_t r64 = (size_t)64 * K;

    auto STAGE = [&](int s, int b) {
        int off = s * 32;
        GLL16(aP + off,       &As[b][w * 16][0]);
        GLL16(aP + r64 + off, &As[b][64 + w * 16][0]);
        GLL16(bP + off,       &Bs[b][w * 16][0]);
        if constexpr (BN == 128) GLL16(bP + r64 + off, &Bs[b][64 + w * 16][0]);
    };

    int NS = K / 32;
    STAGE(0, 0);                            // tile 0 -> buf0
    STAGE(1, 1);                            // tile 1 -> buf1 (stays in flight)
    waitvm<NLD>();                          // buf0 landed; buf1 still in flight
    barrier_lgkm();

    int cb = 0, sb = 2;
    for (int s = 0; s < NS; ++s) {
        if (s + 2 < NS) STAGE(s + 2, sb);   // 2-deep: lands 2 steps from now
        shortx8 af[4], bfv[NJ];
#pragma unroll
        for (int i = 0; i < 4; i++) af[i] = *(const shortx8*)&As[cb][wr + i * 16 + lr][kg * 8];
#pragma unroll
        for (int j = 0; j < NJ; j++) bfv[j] = *(const shortx8*)&Bs[cb][wc + j * 16 + lr][kg * 8];
#pragma unroll
        for (int i = 0; i < 4; i++)
#pragma unroll
            for (int j = 0; j < NJ; j++)
                acc[i][j] = __builtin_amdgcn_mfma_f32_16x16x32_bf16(af[i], bfv[j], acc[i][j], 0, 0, 0);
        if (s + 2 < NS)      waitvm<NLD>(); // tile s+1 landed; tile s+2 in flight
        else if (s + 1 < NS) waitvm<0>();   // epilogue drain
        barrier_lgkm();                     // ds_reads of buf[cb] done in all waves
        cb = (cb == 2) ? 0 : cb + 1;
        sb = (sb == 2) ? 0 : sb + 1;
    }
#pragma unroll
    for (int i = 0; i < 4; i++) {
#pragma unroll
        for (int j = 0; j < NJ; j++) {
            int col = n0 + wc + j * 16 + lr;
            int rbase = m0 + wr + i * 16 + kg * 4;
            float bv = bias ? ldin_f(bias, col, isbf) : 0.f;
#pragma unroll
            for (int r = 0; r < 4; r++) {
                float val = acc[i][j][r] + bv;
                size_t oidx = (size_t)(rbase + r) * N + col;
                if constexpr (MODE == 0) {
                    ((unsigned short*)C)[oidx] = f2bf(val);
                } else if constexpr (MODE == 1) {
                    ((float*)C)[oidx] = val + bf2f(resid[oidx]);
                } else {
                    float a = bf2f(resid[oidx]);               // ao
                    float sg = 1.f / (1.f + __expf(-val));
                    ((unsigned short*)C)[oidx] = f2bf(ldin_f(xin, oidx, isbf) + a * sg);
                }
            }
        }
    }
}

// ---------------- fused MLP-gate GEMM + GLU: act = val * gelu(g) ----------------
// n-major tile order + 3-buffer 2-deep counted-vmcnt pipeline.
__global__ __launch_bounds__(256) void gemm_glu(const unsigned short* __restrict__ A,
                                                const unsigned short* __restrict__ Bt,
                                                unsigned short* __restrict__ act,
                                                const void* __restrict__ bias,
                                                const int* __restrict__ flagp) {
    __shared__ __align__(16) unsigned short As[3][128][32];
    __shared__ __align__(16) unsigned short Bg[3][64][32];
    __shared__ __align__(16) unsigned short Bv[3][64][32];
    const int K = 1024;
    int isbf = *flagp;
    int tile = (blockIdx.x & 7) * (gridDim.x >> 3) + (blockIdx.x >> 3);
    int m0 = (tile & 31) * 128;           // n-major: m fast, n slow within XCD chunk
    int n0 = (tile >> 5) * 64;            // cols 0..4095
    int t = threadIdx.x;
    int lane = t & 63;
    int w = t >> 6;
    int wr = (w >> 1) * 64;               // 2 row-halves
    int wc = (w & 1) * 32;                // 2 col-halves of 32
    int lr = lane & 15;
    int kg = lane >> 4;

    floatx4 ag[4][2], av[4][2];
#pragma unroll
    for (int i = 0; i < 4; i++)
#pragma unroll
        for (int j = 0; j < 2; j++) {
            ag[i][j] = (floatx4){0.f, 0.f, 0.f, 0.f};
            av[i][j] = (floatx4){0.f, 0.f, 0.f, 0.f};
        }

    int srow = w * 16 + (lane >> 2);
    int skseg = (lane & 3) * 8;
    const unsigned short* aP  = A + (size_t)(m0 + srow) * K + skseg;
    const unsigned short* bgP = Bt + (size_t)(n0 + srow) * K + skseg;
    const unsigned short* bvP = Bt + (size_t)(4096 + n0 + srow) * K + skseg;
    size_t r64 = (size_t)64 * K;

    auto STAGE = [&](int s, int b) {
        int off = s * 32;
        GLL16(aP + off,       &As[b][w * 16][0]);
        GLL16(aP + r64 + off, &As[b][64 + w * 16][0]);
        GLL16(bgP + off,      &Bg[b][w * 16][0]);
        GLL16(bvP + off,      &Bv[b][w * 16][0]);
    };

    const int NS = K / 32;                 // 32
    STAGE(0, 0);
    STAGE(1, 1);
    waitvm<4>();
    barrier_lgkm();

    int cb = 0, sb = 2;
    for (int s = 0; s < NS; ++s) {
        if (s + 2 < NS) STAGE(s + 2, sb);
        shortx8 af[4], gf[2], vf[2];
#pragma unroll
        for (int i = 0; i < 4; i++) af[i] = *(const shortx8*)&As[cb][wr + i * 16 + lr][kg * 8];
#pragma unroll
        for (int j = 0; j < 2; j++) {
            gf[j] = *(const shortx8*)&Bg[cb][wc + j * 16 + lr][kg * 8];
            vf[j] = *(const shortx8*)&Bv[cb][wc + j * 16 + lr][kg * 8];
        }
#pragma unroll
        for (int i = 0; i < 4; i++)
#pragma unroll
            for (int j = 0; j < 2; j++) {
                ag[i][j] = __builtin_amdgcn_mfma_f32_16x16x32_bf16(af[i], gf[j], ag[i][j], 0, 0, 0);
                av[i][j] = __builtin_amdgcn_mfma_f32_16x16x32_bf16(af[i], vf[j], av[i][j], 0, 0, 0);
            }
        if (s + 2 < NS)      waitvm<4>();
        else if (s + 1 < NS) waitvm<0>();
        barrier_lgkm();
        cb = (cb == 2) ? 0 : cb + 1;
        sb = (sb == 2) ? 0 : sb + 1;
    }
#pragma unroll
    for (int i = 0; i < 4; i++) {
#pragma unroll
        for (int j = 0; j < 2; j++) {
            int col = n0 + wc + j * 16 + lr;
            int rbase = m0 + wr + i * 16 + kg * 4;
            float bgv = ldin_f(bias, col, isbf);
            float bvv = ldin_f(bias, 4096 + col, isbf);
#pragma unroll
            for (int r = 0; r < 4; r++) {
                float g = ag[i][j][r] + bgv;
                float v = av[i][j][r] + bvv;
                float ge = 0.5f * g * (1.f + erff(g * 0.70710678118f));
                act[(size_t)(rbase + r) * 4096 + col] = f2bf(v * ge);
            }
        }
    }
}

// ---------------- RoPE + relayout to head-major (Householder folded/cancelled) ----
__global__ __launch_bounds__(256) void qk_rope3(const unsigned short* __restrict__ qkv,
                                                const float* __restrict__ tab,
                                                unsigned short* __restrict__ q_r,
                                                unsigned short* __restrict__ k_r) {
    int tid = blockIdx.x * 256 + threadIdx.x;    // = ts*64 + h*4 + c
    int c = tid & 3;
    int h = (tid >> 2) & 15;
    int ts = tid >> 6;
    int s = ts & 2047, b = ts >> 11;
    int d0 = c * 8;
    const unsigned short* base = qkv + (size_t)ts * 3072 + h * 64;
    shortx8 qlo = *(const shortx8*)(base + d0);
    shortx8 qhi = *(const shortx8*)(base + d0 + 32);
    shortx8 klo = *(const shortx8*)(base + 1024 + d0);
    shortx8 khi = *(const shortx8*)(base + 1024 + d0 + 32);
    const float* tp = tab + (size_t)s * 64 + d0 * 2;   // (cos,sin) pairs, fi = d0..d0+7
    shortx8 oql, oqh, okl, okh;
#pragma unroll
    for (int i = 0; i < 8; i++) {
        float cv = tp[2 * i], sv = tp[2 * i + 1];
        float ql = bf2f((unsigned short)qlo[i]), qh = bf2f((unsigned short)qhi[i]);
        float kl = bf2f((unsigned short)klo[i]), kh = bf2f((unsigned short)khi[i]);
        oql[i] = (short)f2bf(ql * cv - qh * sv);
        oqh[i] = (short)f2bf(qh * cv + ql * sv);
        okl[i] = (short)f2bf(kl * cv - kh * sv);
        okh[i] = (short)f2bf(kh * cv + kl * sv);
    }
    size_t o = ((size_t)(b * NH + h) * SEQ + s) * HD + d0;
    *(shortx8*)(q_r + o)      = oql;
    *(shortx8*)(q_r + o + 32) = oqh;
    *(shortx8*)(k_r + o)      = okl;
    *(shortx8*)(k_r + o + 32) = okh;
}

// ---------------- MFMA flash attention (block-causal) v3: swapped QK^T -----------
__global__ __launch_bounds__(512) void attn_mfma(const unsigned short* __restrict__ q_r,
                                                 const unsigned short* __restrict__ k_r,
                                                 const unsigned short* __restrict__ qkv,
                                                 unsigned short* __restrict__ attn) {
    __shared__ __align__(16) unsigned short Ks[64][72];      // [key][dim], +8 pad
    __shared__ __align__(16) unsigned short Vt[64 * 72];     // [dim][72], 8-key blocks XOR-swizzled
    __shared__ __align__(16) unsigned short Ps[8][16][72];   // per-wave P [qrow][key]
    int bid = blockIdx.x;
    int qblk = 15 - (bid & 15);                  // big q-blocks first
    int bh = bid >> 4;
    int b = bh >> 4, h = bh & 15;
    size_t bh_off = (size_t)bh * SEQ * HD;
    int tid = threadIdx.x;
    int wv = tid >> 6, lane = tid & 63;
    int l16 = lane & 15, quad = lane >> 4;
    int q0 = qblk * 128 + wv * 16;

    const unsigned short* qrow = q_r + bh_off + (size_t)(q0 + l16) * HD + quad * 8;
    shortx8 aq0 = *(const shortx8*)(qrow);
    shortx8 aq1 = *(const shortx8*)(qrow + 32);

    floatx4 o[4];
#pragma unroll
    for (int nt = 0; nt < 4; nt++) o[nt] = (floatx4){0.f, 0.f, 0.f, 0.f};
    float m_run = -1e30f, l_run = 0.f;           // this lane owns q-row q0+l16

    int nk = (qblk + 1) * 128;
    int skey = tid >> 3;              // 0..63
    int sd0 = (tid & 7) * 8;          // dim offset
    const unsigned short* kbase = k_r + bh_off + (size_t)skey * HD + sd0;
    const unsigned short* vbase = qkv + ((size_t)(b * SEQ + skey)) * 3072 + 2048 + h * 64 + sd0;
    int vco = (((skey >> 3) ^ (tid & 7)) * 8) + (skey & 7);

    shortx8 kv = *(const shortx8*)kbase;          // prefetch tile 0
    shortx8 vvv = *(const shortx8*)vbase;

    for (int k0 = 0; k0 < nk; k0 += 64) {
        __syncthreads();                          // prev tile's LDS reads done
        *(shortx8*)&Ks[skey][sd0] = kv;
#pragma unroll
        for (int i = 0; i < 8; i++) Vt[(size_t)(sd0 + i) * 72 + vco] = (unsigned short)vvv[i];
        __syncthreads();                          // staged tile visible
        if (k0 + 64 < nk) {                       // prefetch next tile (hidden under compute)
            kv  = *(const shortx8*)(kbase + (size_t)(k0 + 64) * HD);
            vvv = *(const shortx8*)(vbase + (size_t)(k0 + 64) * 3072);
        }

        // swapped QK^T: D[key][q], col=l16=q-row, row=quad*4+r=key (within kt*16)
        floatx4 sc[4];
#pragma unroll
        for (int kt = 0; kt < 4; kt++) {
            shortx8 bk0 = *(const shortx8*)&Ks[kt * 16 + l16][quad * 8];
            shortx8 bk1 = *(const shortx8*)&Ks[kt * 16 + l16][32 + quad * 8];
            floatx4 z = (floatx4){0.f, 0.f, 0.f, 0.f};
            z = __builtin_amdgcn_mfma_f32_16x16x32_bf16(bk0, aq0, z, 0, 0, 0);
            z = __builtin_amdgcn_mfma_f32_16x16x32_bf16(bk1, aq1, z, 0, 0, 0);
            sc[kt] = z;
        }
        // lane holds 16 scores (keys kt*16+quad*4+r) for q-row l16
        float sv[16], mx[16];
#pragma unroll
        for (int kt = 0; kt < 4; kt++)
#pragma unroll
            for (int r = 0; r < 4; r++) sv[kt * 4 + r] = sc[kt][r] * 0.125f;
#pragma unroll
        for (int i = 0; i < 16; i++) mx[i] = sv[i];
#pragma unroll
        for (int st = 8; st > 0; st >>= 1)
#pragma unroll
            for (int i = 0; i < 8; i++)
                if (i < st) mx[i] = fmaxf(mx[i], mx[i + st]);
        float mt = mx[0];
        mt = fmaxf(mt, __shfl_xor(mt, 16, 64));   // reduce over 4 quads
        mt = fmaxf(mt, __shfl_xor(mt, 32, 64));
        float nm = fmaxf(m_run, mt);
        float al = __expf(m_run - nm);
        m_run = nm;
        float p[16];
#pragma unroll
        for (int i = 0; i < 16; i++) p[i] = __expf(sv[i] - nm);
        float sm[8];
#pragma unroll
        for (int i = 0; i < 8; i++) sm[i] = p[i] + p[i + 8];
        float ps = ((sm[0] + sm[1]) + (sm[2] + sm[3])) + ((sm[4] + sm[5]) + (sm[6] + sm[7]));
        ps += __shfl_xor(ps, 16, 64);
        ps += __shfl_xor(ps, 32, 64);
        l_run = l_run * al + ps;
        // P -> LDS as aligned b64 (keys kt*16+quad*4 .. +3 contiguous)
#pragma unroll
        for (int kt = 0; kt < 4; kt++) {
            shortx4 pk;
#pragma unroll
            for (int r = 0; r < 4; r++) pk[r] = (short)f2bf(p[kt * 4 + r]);
            *(shortx4*)&Ps[wv][l16][kt * 16 + quad * 4] = pk;
        }
        // rescale o: o-row quad*4+r needs al from lane l16=quad*4+r
#pragma unroll
        for (int r = 0; r < 4; r++) {
            float alr = __shfl(al, quad * 4 + r, 64);
            o[0][r] *= alr; o[1][r] *= alr; o[2][r] *= alr; o[3][r] *= alr;
        }
        // PV (wave-private Ps RAW: in-order, no barrier)
#pragma unroll
        for (int h2 = 0; h2 < 2; h2++) {
            shortx8 ap = *(const shortx8*)&Ps[wv][l16][h2 * 32 + quad * 8];
#pragma unroll
            for (int nt = 0; nt < 4; nt++) {
                int dd = nt * 16 + l16;
                shortx8 bvv = *(const shortx8*)&Vt[(size_t)dd * 72 +
                                                   (((h2 * 4 + quad) ^ ((dd >> 3) & 7)) * 8)];
                o[nt] = __builtin_amdgcn_mfma_f32_16x16x32_bf16(ap, bvv, o[nt], 0, 0, 0);
            }
        }
    }
#pragma unroll
    for (int r = 0; r < 4; r++) {
        float lv = __shfl(l_run, quad * 4 + r, 64);
        float inv_l = 1.f / lv;
        int s = q0 + quad * 4 + r;
        unsigned short* op = attn + ((size_t)(b * SEQ + s)) * DIM + h * 64;
#pragma unroll
        for (int nt = 0; nt < 4; nt++) op[nt * 16 + l16] = f2bf(o[nt][r] * inv_l);
    }
}

extern "C" void kernel_launch(void* const* d_in, const int* in_sizes, int n_in,
                              void* d_out, int out_size, void* d_ws, size_t ws_size,
                              hipStream_t stream) {
    const unsigned short* x        = (const unsigned short*)d_in[0];
    const void* vs       = d_in[3];
    const void* w_qkv    = d_in[4];
    const void* w_out    = d_in[5];
    const void* w_gate   = d_in[6];
    const void* b_gate   = d_in[7];
    const void* w_mlp_g  = d_in[8];
    const void* b_mlp_g  = d_in[9];
    const void* w_mlp_o  = d_in[10];
    const void* b_mlp_o  = d_in[11];
    float* out = (float*)d_out;    // reference output dtype is float32
    char* ws = (char*)d_ws;

    if (n_in < 12) return;
    if (in_sizes[0] != 4194304 || in_sizes[3] != 2048 || in_sizes[4] != 3145728 ||
        in_sizes[8] != 8388608 || in_sizes[10] != 4194304 || in_sizes[7] != 1024) return;

    const size_t o_T   = 0;            // transposed weights, 35,651,584
    const size_t o_Qg  = 35651584;     // Qg 16 KiB + flag (32 KiB reserved)
    const size_t o_h   = 35684352;     // 8,388,608
    const size_t o_B   = 44072960;     // 25,165,824: qkv (live through attn) | ao after attn
    const size_t o_C   = 69238784;     // q_rb,k_rb,attnb | x1, act after attn
    const size_t o_gv  = 94404608;     // rope table (512 KiB) early
    const size_t total = 161513472;
    if (ws_size < total) return;

    unsigned short* wqkvT  = (unsigned short*)(ws + o_T);             // [3072,1024]
    unsigned short* woutT  = (unsigned short*)(ws + o_T + 6291456);   // [1024,1024]
    unsigned short* wgateT = (unsigned short*)(ws + o_T + 8388608);   // [1024,1024]
    unsigned short* wmgT   = (unsigned short*)(ws + o_T + 10485760);  // [8192,1024]
    unsigned short* wmoT   = (unsigned short*)(ws + o_T + 27262976);  // [1024,4096]
    float*          Qg     = (float*)(ws + o_Qg);
    int*            flagp  = (int*)(ws + o_Qg + 16384);
    unsigned short* h      = (unsigned short*)(ws + o_h);
    unsigned short* qkv    = (unsigned short*)(ws + o_B);             // 24 MiB, live until attn done
    unsigned short* ao     = (unsigned short*)(ws + o_B + 8388608);   // written after attn
    unsigned short* q_rb   = (unsigned short*)(ws + o_C);
    unsigned short* k_rb   = (unsigned short*)(ws + o_C + 8388608);
    unsigned short* attnb  = (unsigned short*)(ws + o_C + 16777216);
    unsigned short* x1     = (unsigned short*)(ws + o_C);             // after attn done
    unsigned short* act    = (unsigned short*)(ws + o_C + 8388608);   // 32 MiB, after attn done
    float*          rtab   = (float*)(ws + o_gv);                     // read only pre-attn

    detect_kernel<<<1, 256, 0, stream>>>(x, flagp);
    householder_kernel<<<1, 64, 0, stream>>>(vs, Qg, flagp);
    rope_table<<<256, 256, 0, stream>>>(rtab);

    dim3 tb(32, 8);
    transpose_any<<<dim3(3072 / 32, 1024 / 32), tb, 0, stream>>>(w_qkv,   wqkvT, 1024, 3072, flagp);
    transpose_any<<<dim3(1024 / 32, 1024 / 32), tb, 0, stream>>>(w_out,   woutT, 1024, 1024, flagp);
    transpose_any<<<dim3(1024 / 32, 1024 / 32), tb, 0, stream>>>(w_gate,  wgateT, 1024, 1024, flagp);
    transpose_any<<<dim3(8192 / 32, 1024 / 32), tb, 0, stream>>>(w_mlp_g, wmgT, 1024, 8192, flagp);
    transpose_any<<<dim3(1024 / 32, 4096 / 32), tb, 0, stream>>>(w_mlp_o, wmoT, 4096, 1024, flagp);
    rotate_wqkv<<<256, 256, 0, stream>>>(wqkvT, Qg);   // fold q = (h Wq) Q^T into weights

    rmsnorm2<<<NTOK, 256, 0, stream>>>(x, h, flagp);
    gemm_bt<128, 0><<<32 * 24, 256, 0, stream>>>(h, wqkvT, qkv, nullptr, nullptr, nullptr, flagp, NTOK, 3072, 1024);
    qk_rope3<<<1024, 256, 0, stream>>>(qkv, rtab, q_rb, k_rb);
    attn_mfma<<<BT * NH * (SEQ / 128), 512, 0, stream>>>(q_rb, k_rb, qkv, attnb);
    gemm_bt<64, 0><<<32 * 16, 256, 0, stream>>>(attnb, woutT, ao, nullptr, nullptr, nullptr, flagp, NTOK, 1024, 1024);
    // gate GEMM fused with combine: x1 = x + ao * sigmoid(ao@Wg + bg)
    gemm_bt<64, 2><<<32 * 16, 256, 0, stream>>>(ao, wgateT, x1, b_gate, ao, x, flagp, NTOK, 1024, 1024);
    rmsnorm2<<<NTOK, 256, 0, stream>>>(x1, h, nullptr);
    gemm_glu<<<32 * 64, 256, 0, stream>>>(h, wmgT, act, b_mlp_g, flagp);
    gemm_bt<64, 1><<<32 * 16, 256, 0, stream>>>(act, wmoT, (void*)out, b_mlp_o, x1, nullptr, flagp, NTOK, 1024, 4096);
}

// Round 11
// 541.427 us; speedup vs baseline: 1.0538x; 1.0538x over previous
//
#include <hip/hip_runtime.h>
#include <hip/hip_bf16.h>
#include <math.h>

#define BT 2
#define SEQ 2048
#define DIM 1024
#define NH 16
#define HD 64
#define NTOK (BT*SEQ)          // 4096

typedef __attribute__((ext_vector_type(4))) float floatx4;
typedef __attribute__((ext_vector_type(8))) short shortx8;   // 8 bf16 = 4 VGPRs (MFMA frag)
typedef __attribute__((ext_vector_type(4))) short shortx4;

// async global->LDS, 16B per lane; dest is wave-uniform base + lane*16
#define GLL16(gp, lp) __builtin_amdgcn_global_load_lds( \
    (const __attribute__((address_space(1))) unsigned int*)(const void*)(gp), \
    (__attribute__((address_space(3))) unsigned int*)(void*)(lp), 16, 0, 0)

__device__ __forceinline__ float bf2f(unsigned short u) {
    unsigned int x = ((unsigned int)u) << 16;
    return __builtin_bit_cast(float, x);
}
__device__ __forceinline__ unsigned short f2bf(float f) {
    unsigned int x = __builtin_bit_cast(unsigned int, f);
    unsigned int lsb = (x >> 16) & 1u;
    x += 0x7fffu + lsb;
    return (unsigned short)(x >> 16);
}
// dual-dtype input read: isbf=1 -> bf16, else fp32 (validated: inputs are fp32)
__device__ __forceinline__ float ldin_f(const void* p, size_t i, int isbf) {
    return isbf ? bf2f(((const unsigned short*)p)[i]) : ((const float*)p)[i];
}

// ---------------- input dtype detection (validated R1->R2) ----------------
__global__ void detect_kernel(const unsigned short* __restrict__ x, int* __restrict__ flag) {
    __shared__ int cnt;
    if (threadIdx.x == 0) cnt = 0;
    __syncthreads();
    unsigned short u = x[(size_t)threadIdx.x * 2];
    int e = (u >> 7) & 0xFF;
    if (e >= 100 && e <= 140) atomicAdd(&cnt, 1);
    __syncthreads();
    if (threadIdx.x == 0) *flag = (cnt >= 192) ? 1 : 0;
}

// ---------------- transpose (any float dtype -> bf16) ----------------
__global__ void transpose_any(const void* __restrict__ in,
                              unsigned short* __restrict__ out, int R, int C,
                              const int* __restrict__ flagp) {
    int isbf = *flagp;
    __shared__ unsigned short tile[32][33];
    int c0 = blockIdx.x * 32, r0 = blockIdx.y * 32;
    int tx = threadIdx.x, ty = threadIdx.y;
#pragma unroll
    for (int i = 0; i < 4; i++) {
        size_t idx = (size_t)(r0 + ty + i * 8) * C + c0 + tx;
        tile[ty + i * 8][tx] = isbf ? ((const unsigned short*)in)[idx]
                                    : f2bf(((const float*)in)[idx]);
    }
    __syncthreads();
#pragma unroll
    for (int i = 0; i < 4; i++)
        out[(size_t)(c0 + ty + i * 8) * R + r0 + tx] = tile[tx][ty + i * 8];
}

// ---------------- Householder Q (64x64 fp32), register-resident columns ----------
__global__ __launch_bounds__(64) void householder_kernel(const void* __restrict__ vs,
                                                         float* __restrict__ Qg,
                                                         const int* __restrict__ flagp) {
    int isbf = *flagp;
    __shared__ float vsh[64];
    int j = threadIdx.x;
    float Qc[64];
#pragma unroll
    for (int i = 0; i < 64; i++) Qc[i] = (i == j) ? 1.f : 0.f;
    for (int r = 0; r < 32; r++) {
        vsh[j] = ldin_f(vs, r * 64 + j, isbf);
        __syncthreads();
        float va[64];
#pragma unroll
        for (int i = 0; i < 64; i++) va[i] = vsh[i];
        float vn0 = 0.f, vn1 = 0.f, vn2 = 0.f, vn3 = 0.f;
        float t0 = 0.f, t1 = 0.f, t2 = 0.f, t3 = 0.f;
#pragma unroll
        for (int i = 0; i < 16; i++) {
            vn0 += va[4 * i + 0] * va[4 * i + 0];
            vn1 += va[4 * i + 1] * va[4 * i + 1];
            vn2 += va[4 * i + 2] * va[4 * i + 2];
            vn3 += va[4 * i + 3] * va[4 * i + 3];
            t0 += va[4 * i + 0] * Qc[4 * i + 0];
            t1 += va[4 * i + 1] * Qc[4 * i + 1];
            t2 += va[4 * i + 2] * Qc[4 * i + 2];
            t3 += va[4 * i + 3] * Qc[4 * i + 3];
        }
        float vn = (vn0 + vn1) + (vn2 + vn3) + 1e-8f;
        float t = (t0 + t1) + (t2 + t3);
        float c = (2.f / vn) * t;
#pragma unroll
        for (int i = 0; i < 64; i++) Qc[i] -= c * va[i];
        __syncthreads();
    }
#pragma unroll
    for (int i = 0; i < 64; i++) Qg[i * 64 + j] = Qc[i];
}

// ---------------- pre-rotate q,k head-blocks of wqkvT by Q: W'[hb] = Q @ W[hb] ----
__global__ __launch_bounds__(256) void rotate_wqkv(unsigned short* __restrict__ wT,
                                                   const float* __restrict__ Qg) {
    __shared__ float Qs[64][64];
    __shared__ unsigned short tile[64][128];
    int bid = blockIdx.x;
    int row0 = (bid >> 3) * 64;      // head-block base row (0..2047)
    int col0 = (bid & 7) * 128;      // column chunk
    int t = threadIdx.x;
#pragma unroll
    for (int i = 0; i < 16; i++) {
        int idx = i * 256 + t;
        Qs[idx >> 6][idx & 63] = Qg[idx];
    }
#pragma unroll
    for (int i = 0; i < 8; i++) {
        int e = i * 256 + t;
        int r = e >> 5, cg = (e & 31) * 4;
        *(shortx4*)&tile[r][cg] = *(const shortx4*)&wT[(size_t)(row0 + r) * 1024 + col0 + cg];
    }
    __syncthreads();
    int ib = t >> 5;                 // 0..7
    int c = (t & 31) * 4;
    float acc[8][4];
#pragma unroll
    for (int rr = 0; rr < 8; rr++)
#pragma unroll
        for (int cx = 0; cx < 4; cx++) acc[rr][cx] = 0.f;
    for (int j = 0; j < 64; j++) {
        float t0 = bf2f(tile[j][c]);
        float t1 = bf2f(tile[j][c + 1]);
        float t2 = bf2f(tile[j][c + 2]);
        float t3 = bf2f(tile[j][c + 3]);
#pragma unroll
        for (int rr = 0; rr < 8; rr++) {
            float qv = Qs[rr * 8 + ib][j];
            acc[rr][0] += qv * t0;
            acc[rr][1] += qv * t1;
            acc[rr][2] += qv * t2;
            acc[rr][3] += qv * t3;
        }
    }
#pragma unroll
    for (int rr = 0; rr < 8; rr++) {
        int i = rr * 8 + ib;
        shortx4 o4;
#pragma unroll
        for (int cx = 0; cx < 4; cx++) o4[cx] = (short)f2bf(acc[rr][cx]);
        *(shortx4*)&wT[(size_t)(row0 + i) * 1024 + col0 + c] = o4;
    }
}

// ---------------- rope cos/sin table [2048][32] interleaved (cos,sin) ----------
__global__ void rope_table(float* __restrict__ tab) {
    int idx = blockIdx.x * 256 + threadIdx.x;    // s*32 + fi
    int s = idx >> 5, fi = idx & 31;
    float invf = __expf(-(float)fi * (9.210340371976184f / 32.f));  // 10000^(-fi/32)
    float ang = (float)s * invf;
    tab[2 * idx]     = cosf(ang);
    tab[2 * idx + 1] = sinf(ang);
}

// ---------------- rmsnorm over D=1024, LDS tree reduction ----------------
__global__ __launch_bounds__(256) void rmsnorm2(const void* __restrict__ x,
                                                unsigned short* __restrict__ h,
                                                const int* __restrict__ flagp) {
    int isbf = flagp ? *flagp : 1;
    __shared__ float red[256];
    int row = blockIdx.x, t = threadIdx.x;
    size_t base = (size_t)row * DIM;
    float v[4];
    float ss = 0.f;
#pragma unroll
    for (int i = 0; i < 4; i++) {
        v[i] = ldin_f(x, base + t + 256 * i, isbf);
        ss += v[i] * v[i];
    }
    red[t] = ss;
    __syncthreads();
    for (int s = 128; s > 0; s >>= 1) {
        if (t < s) red[t] += red[t + s];
        __syncthreads();
    }
    float rs = rsqrtf(red[0] * (1.f / 1024.f) + 1e-6f);
#pragma unroll
    for (int i = 0; i < 4; i++) h[base + t + 256 * i] = f2bf(v[i] * rs);
}

// ---------------- MFMA GEMM: BK=64, XOR-swizzled LDS, dbuf, unrolled 2-phase -----
// T2 swizzle (rule #21): linear GLL dest + inverse-swizzled GLOBAL source
// (seg_g = (lane&7)^(row&7), lane-constant) + swizzled ds_read col
// ((kk*4+kg)^(lr&7)) -> conflict-free b128 reads at 128B row stride.
// Unrolled x2 so buffer indices are literals (ds offsets fold to immediates).
// MODE: 0=bf16 store, 1=f32+resid, 2=gated combine x1=xin+resid*sigmoid(val+bias).
template<int MODE>
__global__ __launch_bounds__(256) void gemm_bt(const unsigned short* __restrict__ A,
                                               const unsigned short* __restrict__ Bt,
                                               void* __restrict__ C,
                                               const void* __restrict__ bias,
                                               const unsigned short* __restrict__ resid,
                                               const void* __restrict__ xin,
                                               const int* __restrict__ flagp,
                                               int M, int N, int K) {
    __shared__ __align__(16) unsigned short As[2][128][64];   // 32 KB
    __shared__ __align__(16) unsigned short Bs[2][64][64];    // 16 KB
    int isbf = flagp ? *flagp : 1;
    int tile = (blockIdx.x & 7) * (gridDim.x >> 3) + (blockIdx.x >> 3);
    int nbn = N >> 6;
    int m0 = (tile / nbn) * 128;             // n fast: A-panel reused across n-sweep
    int n0 = (tile % nbn) * 64;
    int t = threadIdx.x;
    int lane = t & 63;
    int w = t >> 6;
    int wr = (w >> 1) * 64;
    int wc = (w & 1) * 32;
    int lr = lane & 15;
    int kg = lane >> 4;
    int l8 = lane >> 3, s8 = lane & 7;
    int segswz = (s8 ^ l8) * 8;              // global col offset (shorts), lane-const
    int cs0 = ((kg)     ^ (lr & 7)) * 8;     // LDS col (shorts), kk=0
    int cs1 = ((4 + kg) ^ (lr & 7)) * 8;     // kk=1

    floatx4 acc[4][2];
#pragma unroll
    for (int i = 0; i < 4; i++)
#pragma unroll
        for (int j = 0; j < 2; j++) acc[i][j] = (floatx4){0.f, 0.f, 0.f, 0.f};

    int rbase = w * 8 + l8;                  // staged row within 32-row group
    const unsigned short* aP0 = A + (size_t)(m0 + rbase +  0) * K + segswz;
    const unsigned short* aP1 = A + (size_t)(m0 + rbase + 32) * K + segswz;
    const unsigned short* aP2 = A + (size_t)(m0 + rbase + 64) * K + segswz;
    const unsigned short* aP3 = A + (size_t)(m0 + rbase + 96) * K + segswz;
    const unsigned short* bP0 = Bt + (size_t)(n0 + rbase +  0) * K + segswz;
    const unsigned short* bP1 = Bt + (size_t)(n0 + rbase + 32) * K + segswz;

    auto STAGE = [&](int s, int B) {
        int off = s * 64;
        GLL16(aP0 + off, &As[B][w * 8 +  0][0]);
        GLL16(aP1 + off, &As[B][w * 8 + 32][0]);
        GLL16(aP2 + off, &As[B][w * 8 + 64][0]);
        GLL16(aP3 + off, &As[B][w * 8 + 96][0]);
        GLL16(bP0 + off, &Bs[B][w * 8 +  0][0]);
        GLL16(bP1 + off, &Bs[B][w * 8 + 32][0]);
    };
    auto MM = [&](int B) {
        shortx8 af[4][2], bf[2][2];
#pragma unroll
        for (int i = 0; i < 4; i++) {
            af[i][0] = *(const shortx8*)&As[B][wr + i * 16 + lr][cs0];
            af[i][1] = *(const shortx8*)&As[B][wr + i * 16 + lr][cs1];
        }
#pragma unroll
        for (int j = 0; j < 2; j++) {
            bf[j][0] = *(const shortx8*)&Bs[B][wc + j * 16 + lr][cs0];
            bf[j][1] = *(const shortx8*)&Bs[B][wc + j * 16 + lr][cs1];
        }
#pragma unroll
        for (int i = 0; i < 4; i++)
#pragma unroll
            for (int j = 0; j < 2; j++) {
                acc[i][j] = __builtin_amdgcn_mfma_f32_16x16x32_bf16(af[i][0], bf[j][0], acc[i][j], 0, 0, 0);
                acc[i][j] = __builtin_amdgcn_mfma_f32_16x16x32_bf16(af[i][1], bf[j][1], acc[i][j], 0, 0, 0);
            }
    };

    int NS = K >> 6;                         // K multiple of 128 -> NS even
    STAGE(0, 0);
    __syncthreads();
    for (int s = 0; s < NS; s += 2) {
        if (s + 1 < NS) STAGE(s + 1, 1);     // prefetch hides under compute
        MM(0);
        __syncthreads();                     // vmcnt(0)+barrier: buf1 ready, buf0 free
        if (s + 1 < NS) {
            if (s + 2 < NS) STAGE(s + 2, 0);
            MM(1);
            __syncthreads();
        }
    }
#pragma unroll
    for (int i = 0; i < 4; i++) {
#pragma unroll
        for (int j = 0; j < 2; j++) {
            int col = n0 + wc + j * 16 + lr;
            int rb = m0 + wr + i * 16 + kg * 4;
            float bv = bias ? ldin_f(bias, col, isbf) : 0.f;
#pragma unroll
            for (int r = 0; r < 4; r++) {
                float val = acc[i][j][r] + bv;
                size_t oidx = (size_t)(rb + r) * N + col;
                if constexpr (MODE == 0) {
                    ((unsigned short*)C)[oidx] = f2bf(val);
                } else if constexpr (MODE == 1) {
                    ((float*)C)[oidx] = val + bf2f(resid[oidx]);
                } else {
                    float a = bf2f(resid[oidx]);               // ao
                    float sg = 1.f / (1.f + __expf(-val));
                    ((unsigned short*)C)[oidx] = f2bf(ldin_f(xin, oidx, isbf) + a * sg);
                }
            }
        }
    }
}

// ---------------- fused MLP-gate GEMM + GLU: act = val * gelu(g) ----------------
// n-major tile order; BK=64 + swizzle + dbuf unrolled 2-phase (as gemm_bt).
__global__ __launch_bounds__(256) void gemm_glu(const unsigned short* __restrict__ A,
                                                const unsigned short* __restrict__ Bt,
                                                unsigned short* __restrict__ act,
                                                const void* __restrict__ bias,
                                                const int* __restrict__ flagp) {
    __shared__ __align__(16) unsigned short As[2][128][64];   // 32 KB
    __shared__ __align__(16) unsigned short Bg[2][64][64];    // 16 KB
    __shared__ __align__(16) unsigned short Bv[2][64][64];    // 16 KB
    const int K = 1024;
    int isbf = *flagp;
    int tile = (blockIdx.x & 7) * (gridDim.x >> 3) + (blockIdx.x >> 3);
    int m0 = (tile & 31) * 128;           // n-major: m fast within XCD chunk
    int n0 = (tile >> 5) * 64;            // cols 0..4095
    int t = threadIdx.x;
    int lane = t & 63;
    int w = t >> 6;
    int wr = (w >> 1) * 64;
    int wc = (w & 1) * 32;
    int lr = lane & 15;
    int kg = lane >> 4;
    int l8 = lane >> 3, s8 = lane & 7;
    int segswz = (s8 ^ l8) * 8;
    int cs0 = ((kg)     ^ (lr & 7)) * 8;
    int cs1 = ((4 + kg) ^ (lr & 7)) * 8;

    floatx4 ag[4][2], av[4][2];
#pragma unroll
    for (int i = 0; i < 4; i++)
#pragma unroll
        for (int j = 0; j < 2; j++) {
            ag[i][j] = (floatx4){0.f, 0.f, 0.f, 0.f};
            av[i][j] = (floatx4){0.f, 0.f, 0.f, 0.f};
        }

    int rbase = w * 8 + l8;
    const unsigned short* aP0 = A + (size_t)(m0 + rbase +  0) * K + segswz;
    const unsigned short* aP1 = A + (size_t)(m0 + rbase + 32) * K + segswz;
    const unsigned short* aP2 = A + (size_t)(m0 + rbase + 64) * K + segswz;
    const unsigned short* aP3 = A + (size_t)(m0 + rbase + 96) * K + segswz;
    const unsigned short* gP0 = Bt + (size_t)(n0 + rbase +  0) * K + segswz;
    const unsigned short* gP1 = Bt + (size_t)(n0 + rbase + 32) * K + segswz;
    const unsigned short* vP0 = Bt + (size_t)(4096 + n0 + rbase +  0) * K + segswz;
    const unsigned short* vP1 = Bt + (size_t)(4096 + n0 + rbase + 32) * K + segswz;

    auto STAGE = [&](int s, int B) {
        int off = s * 64;
        GLL16(aP0 + off, &As[B][w * 8 +  0][0]);
        GLL16(aP1 + off, &As[B][w * 8 + 32][0]);
        GLL16(aP2 + off, &As[B][w * 8 + 64][0]);
        GLL16(aP3 + off, &As[B][w * 8 + 96][0]);
        GLL16(gP0 + off, &Bg[B][w * 8 +  0][0]);
        GLL16(gP1 + off, &Bg[B][w * 8 + 32][0]);
        GLL16(vP0 + off, &Bv[B][w * 8 +  0][0]);
        GLL16(vP1 + off, &Bv[B][w * 8 + 32][0]);
    };
    auto MM = [&](int B) {
        shortx8 af[4][2], gf[2][2], vf[2][2];
#pragma unroll
        for (int i = 0; i < 4; i++) {
            af[i][0] = *(const shortx8*)&As[B][wr + i * 16 + lr][cs0];
            af[i][1] = *(const shortx8*)&As[B][wr + i * 16 + lr][cs1];
        }
#pragma unroll
        for (int j = 0; j < 2; j++) {
            gf[j][0] = *(const shortx8*)&Bg[B][wc + j * 16 + lr][cs0];
            gf[j][1] = *(const shortx8*)&Bg[B][wc + j * 16 + lr][cs1];
            vf[j][0] = *(const shortx8*)&Bv[B][wc + j * 16 + lr][cs0];
            vf[j][1] = *(const shortx8*)&Bv[B][wc + j * 16 + lr][cs1];
        }
#pragma unroll
        for (int i = 0; i < 4; i++)
#pragma unroll
            for (int j = 0; j < 2; j++) {
                ag[i][j] = __builtin_amdgcn_mfma_f32_16x16x32_bf16(af[i][0], gf[j][0], ag[i][j], 0, 0, 0);
                ag[i][j] = __builtin_amdgcn_mfma_f32_16x16x32_bf16(af[i][1], gf[j][1], ag[i][j], 0, 0, 0);
                av[i][j] = __builtin_amdgcn_mfma_f32_16x16x32_bf16(af[i][0], vf[j][0], av[i][j], 0, 0, 0);
                av[i][j] = __builtin_amdgcn_mfma_f32_16x16x32_bf16(af[i][1], vf[j][1], av[i][j], 0, 0, 0);
            }
    };

    const int NS = K >> 6;                   // 16
    STAGE(0, 0);
    __syncthreads();
    for (int s = 0; s < NS; s += 2) {
        if (s + 1 < NS) STAGE(s + 1, 1);
        MM(0);
        __syncthreads();
        if (s + 1 < NS) {
            if (s + 2 < NS) STAGE(s + 2, 0);
            MM(1);
            __syncthreads();
        }
    }
#pragma unroll
    for (int i = 0; i < 4; i++) {
#pragma unroll
        for (int j = 0; j < 2; j++) {
            int col = n0 + wc + j * 16 + lr;
            int rb = m0 + wr + i * 16 + kg * 4;
            float bgv = ldin_f(bias, col, isbf);
            float bvv = ldin_f(bias, 4096 + col, isbf);
#pragma unroll
            for (int r = 0; r < 4; r++) {
                float g = ag[i][j][r] + bgv;
                float v = av[i][j][r] + bvv;
                float ge = 0.5f * g * (1.f + erff(g * 0.70710678118f));
                act[(size_t)(rb + r) * 4096 + col] = f2bf(v * ge);
            }
        }
    }
}

// ---------------- RoPE + relayout to head-major (Householder folded/cancelled) ----
__global__ __launch_bounds__(256) void qk_rope3(const unsigned short* __restrict__ qkv,
                                                const float* __restrict__ tab,
                                                unsigned short* __restrict__ q_r,
                                                unsigned short* __restrict__ k_r) {
    int tid = blockIdx.x * 256 + threadIdx.x;    // = ts*64 + h*4 + c
    int c = tid & 3;
    int h = (tid >> 2) & 15;
    int ts = tid >> 6;
    int s = ts & 2047, b = ts >> 11;
    int d0 = c * 8;
    const unsigned short* base = qkv + (size_t)ts * 3072 + h * 64;
    shortx8 qlo = *(const shortx8*)(base + d0);
    shortx8 qhi = *(const shortx8*)(base + d0 + 32);
    shortx8 klo = *(const shortx8*)(base + 1024 + d0);
    shortx8 khi = *(const shortx8*)(base + 1024 + d0 + 32);
    const float* tp = tab + (size_t)s * 64 + d0 * 2;   // (cos,sin) pairs, fi = d0..d0+7
    shortx8 oql, oqh, okl, okh;
#pragma unroll
    for (int i = 0; i < 8; i++) {
        float cv = tp[2 * i], sv = tp[2 * i + 1];
        float ql = bf2f((unsigned short)qlo[i]), qh = bf2f((unsigned short)qhi[i]);
        float kl = bf2f((unsigned short)klo[i]), kh = bf2f((unsigned short)khi[i]);
        oql[i] = (short)f2bf(ql * cv - qh * sv);
        oqh[i] = (short)f2bf(qh * cv + ql * sv);
        okl[i] = (short)f2bf(kl * cv - kh * sv);
        okh[i] = (short)f2bf(kh * cv + kl * sv);
    }
    size_t o = ((size_t)(b * NH + h) * SEQ + s) * HD + d0;
    *(shortx8*)(q_r + o)      = oql;
    *(shortx8*)(q_r + o + 32) = oqh;
    *(shortx8*)(k_r + o)      = okl;
    *(shortx8*)(k_r + o + 32) = okh;
}

// ---------------- MFMA flash attention (block-causal) v3: swapped QK^T -----------
__global__ __launch_bounds__(512) void attn_mfma(const unsigned short* __restrict__ q_r,
                                                 const unsigned short* __restrict__ k_r,
                                                 const unsigned short* __restrict__ qkv,
                                                 unsigned short* __restrict__ attn) {
    __shared__ __align__(16) unsigned short Ks[64][72];      // [key][dim], +8 pad
    __shared__ __align__(16) unsigned short Vt[64 * 72];     // [dim][72], 8-key blocks XOR-swizzled
    __shared__ __align__(16) unsigned short Ps[8][16][72];   // per-wave P [qrow][key]
    int bid = blockIdx.x;
    int qblk = 15 - (bid & 15);                  // big q-blocks first
    int bh = bid >> 4;
    int b = bh >> 4, h = bh & 15;
    size_t bh_off = (size_t)bh * SEQ * HD;
    int tid = threadIdx.x;
    int wv = tid >> 6, lane = tid & 63;
    int l16 = lane & 15, quad = lane >> 4;
    int q0 = qblk * 128 + wv * 16;

    const unsigned short* qrow = q_r + bh_off + (size_t)(q0 + l16) * HD + quad * 8;
    shortx8 aq0 = *(const shortx8*)(qrow);
    shortx8 aq1 = *(const shortx8*)(qrow + 32);

    floatx4 o[4];
#pragma unroll
    for (int nt = 0; nt < 4; nt++) o[nt] = (floatx4){0.f, 0.f, 0.f, 0.f};
    float m_run = -1e30f, l_run = 0.f;           // this lane owns q-row q0+l16

    int nk = (qblk + 1) * 128;
    int skey = tid >> 3;              // 0..63
    int sd0 = (tid & 7) * 8;          // dim offset
    const unsigned short* kbase = k_r + bh_off + (size_t)skey * HD + sd0;
    const unsigned short* vbase = qkv + ((size_t)(b * SEQ + skey)) * 3072 + 2048 + h * 64 + sd0;
    int vco = (((skey >> 3) ^ (tid & 7)) * 8) + (skey & 7);

    shortx8 kv = *(const shortx8*)kbase;          // prefetch tile 0
    shortx8 vvv = *(const shortx8*)vbase;

    for (int k0 = 0; k0 < nk; k0 += 64) {
        __syncthreads();                          // prev tile's LDS reads done
        *(shortx8*)&Ks[skey][sd0] = kv;
#pragma unroll
        for (int i = 0; i < 8; i++) Vt[(size_t)(sd0 + i) * 72 + vco] = (unsigned short)vvv[i];
        __syncthreads();                          // staged tile visible
        if (k0 + 64 < nk) {                       // prefetch next tile (hidden under compute)
            kv  = *(const shortx8*)(kbase + (size_t)(k0 + 64) * HD);
            vvv = *(const shortx8*)(vbase + (size_t)(k0 + 64) * 3072);
        }

        // swapped QK^T: D[key][q], col=l16=q-row, row=quad*4+r=key (within kt*16)
        floatx4 sc[4];
#pragma unroll
        for (int kt = 0; kt < 4; kt++) {
            shortx8 bk0 = *(const shortx8*)&Ks[kt * 16 + l16][quad * 8];
            shortx8 bk1 = *(const shortx8*)&Ks[kt * 16 + l16][32 + quad * 8];
            floatx4 z = (floatx4){0.f, 0.f, 0.f, 0.f};
            z = __builtin_amdgcn_mfma_f32_16x16x32_bf16(bk0, aq0, z, 0, 0, 0);
            z = __builtin_amdgcn_mfma_f32_16x16x32_bf16(bk1, aq1, z, 0, 0, 0);
            sc[kt] = z;
        }
        // lane holds 16 scores (keys kt*16+quad*4+r) for q-row l16
        float sv[16], mx[16];
#pragma unroll
        for (int kt = 0; kt < 4; kt++)
#pragma unroll
            for (int r = 0; r < 4; r++) sv[kt * 4 + r] = sc[kt][r] * 0.125f;
#pragma unroll
        for (int i = 0; i < 16; i++) mx[i] = sv[i];
#pragma unroll
        for (int st = 8; st > 0; st >>= 1)
#pragma unroll
            for (int i = 0; i < 8; i++)
                if (i < st) mx[i] = fmaxf(mx[i], mx[i + st]);
        float mt = mx[0];
        mt = fmaxf(mt, __shfl_xor(mt, 16, 64));   // reduce over 4 quads
        mt = fmaxf(mt, __shfl_xor(mt, 32, 64));
        float nm = fmaxf(m_run, mt);
        float al = __expf(m_run - nm);
        m_run = nm;
        float p[16];
#pragma unroll
        for (int i = 0; i < 16; i++) p[i] = __expf(sv[i] - nm);
        float sm[8];
#pragma unroll
        for (int i = 0; i < 8; i++) sm[i] = p[i] + p[i + 8];
        float ps = ((sm[0] + sm[1]) + (sm[2] + sm[3])) + ((sm[4] + sm[5]) + (sm[6] + sm[7]));
        ps += __shfl_xor(ps, 16, 64);
        ps += __shfl_xor(ps, 32, 64);
        l_run = l_run * al + ps;
        // P -> LDS as aligned b64 (keys kt*16+quad*4 .. +3 contiguous)
#pragma unroll
        for (int kt = 0; kt < 4; kt++) {
            shortx4 pk;
#pragma unroll
            for (int r = 0; r < 4; r++) pk[r] = (short)f2bf(p[kt * 4 + r]);
            *(shortx4*)&Ps[wv][l16][kt * 16 + quad * 4] = pk;
        }
        // rescale o: o-row quad*4+r needs al from lane l16=quad*4+r
#pragma unroll
        for (int r = 0; r < 4; r++) {
            float alr = __shfl(al, quad * 4 + r, 64);
            o[0][r] *= alr; o[1][r] *= alr; o[2][r] *= alr; o[3][r] *= alr;
        }
        // PV (wave-private Ps RAW: in-order, no barrier)
#pragma unroll
        for (int h2 = 0; h2 < 2; h2++) {
            shortx8 ap = *(const shortx8*)&Ps[wv][l16][h2 * 32 + quad * 8];
#pragma unroll
            for (int nt = 0; nt < 4; nt++) {
                int dd = nt * 16 + l16;
                shortx8 bvv = *(const shortx8*)&Vt[(size_t)dd * 72 +
                                                   (((h2 * 4 + quad) ^ ((dd >> 3) & 7)) * 8)];
                o[nt] = __builtin_amdgcn_mfma_f32_16x16x32_bf16(ap, bvv, o[nt], 0, 0, 0);
            }
        }
    }
#pragma unroll
    for (int r = 0; r < 4; r++) {
        float lv = __shfl(l_run, quad * 4 + r, 64);
        float inv_l = 1.f / lv;
        int s = q0 + quad * 4 + r;
        unsigned short* op = attn + ((size_t)(b * SEQ + s)) * DIM + h * 64;
#pragma unroll
        for (int nt = 0; nt < 4; nt++) op[nt * 16 + l16] = f2bf(o[nt][r] * inv_l);
    }
}

extern "C" void kernel_launch(void* const* d_in, const int* in_sizes, int n_in,
                              void* d_out, int out_size, void* d_ws, size_t ws_size,
                              hipStream_t stream) {
    const unsigned short* x        = (const unsigned short*)d_in[0];
    const void* vs       = d_in[3];
    const void* w_qkv    = d_in[4];
    const void* w_out    = d_in[5];
    const void* w_gate   = d_in[6];
    const void* b_gate   = d_in[7];
    const void* w_mlp_g  = d_in[8];
    const void* b_mlp_g  = d_in[9];
    const void* w_mlp_o  = d_in[10];
    const void* b_mlp_o  = d_in[11];
    float* out = (float*)d_out;    // reference output dtype is float32
    char* ws = (char*)d_ws;

    if (n_in < 12) return;
    if (in_sizes[0] != 4194304 || in_sizes[3] != 2048 || in_sizes[4] != 3145728 ||
        in_sizes[8] != 8388608 || in_sizes[10] != 4194304 || in_sizes[7] != 1024) return;

    const size_t o_T   = 0;            // transposed weights, 35,651,584
    const size_t o_Qg  = 35651584;     // Qg 16 KiB + flag (32 KiB reserved)
    const size_t o_h   = 35684352;     // 8,388,608
    const size_t o_B   = 44072960;     // 25,165,824: qkv (live through attn) | ao after attn
    const size_t o_C   = 69238784;     // q_rb,k_rb,attnb | x1, act after attn
    const size_t o_gv  = 94404608;     // rope table (512 KiB) early
    const size_t total = 161513472;
    if (ws_size < total) return;

    unsigned short* wqkvT  = (unsigned short*)(ws + o_T);             // [3072,1024]
    unsigned short* woutT  = (unsigned short*)(ws + o_T + 6291456);   // [1024,1024]
    unsigned short* wgateT = (unsigned short*)(ws + o_T + 8388608);   // [1024,1024]
    unsigned short* wmgT   = (unsigned short*)(ws + o_T + 10485760);  // [8192,1024]
    unsigned short* wmoT   = (unsigned short*)(ws + o_T + 27262976);  // [1024,4096]
    float*          Qg     = (float*)(ws + o_Qg);
    int*            flagp  = (int*)(ws + o_Qg + 16384);
    unsigned short* h      = (unsigned short*)(ws + o_h);
    unsigned short* qkv    = (unsigned short*)(ws + o_B);             // 24 MiB, live until attn done
    unsigned short* ao     = (unsigned short*)(ws + o_B + 8388608);   // written after attn
    unsigned short* q_rb   = (unsigned short*)(ws + o_C);
    unsigned short* k_rb   = (unsigned short*)(ws + o_C + 8388608);
    unsigned short* attnb  = (unsigned short*)(ws + o_C + 16777216);
    unsigned short* x1     = (unsigned short*)(ws + o_C);             // after attn done
    unsigned short* act    = (unsigned short*)(ws + o_C + 8388608);   // 32 MiB, after attn done
    float*          rtab   = (float*)(ws + o_gv);                     // read only pre-attn

    detect_kernel<<<1, 256, 0, stream>>>(x, flagp);
    householder_kernel<<<1, 64, 0, stream>>>(vs, Qg, flagp);
    rope_table<<<256, 256, 0, stream>>>(rtab);

    dim3 tb(32, 8);
    transpose_any<<<dim3(3072 / 32, 1024 / 32), tb, 0, stream>>>(w_qkv,   wqkvT, 1024, 3072, flagp);
    transpose_any<<<dim3(1024 / 32, 1024 / 32), tb, 0, stream>>>(w_out,   woutT, 1024, 1024, flagp);
    transpose_any<<<dim3(1024 / 32, 1024 / 32), tb, 0, stream>>>(w_gate,  wgateT, 1024, 1024, flagp);
    transpose_any<<<dim3(8192 / 32, 1024 / 32), tb, 0, stream>>>(w_mlp_g, wmgT, 1024, 8192, flagp);
    transpose_any<<<dim3(1024 / 32, 4096 / 32), tb, 0, stream>>>(w_mlp_o, wmoT, 4096, 1024, flagp);
    rotate_wqkv<<<256, 256, 0, stream>>>(wqkvT, Qg);   // fold q = (h Wq) Q^T into weights

    rmsnorm2<<<NTOK, 256, 0, stream>>>(x, h, flagp);
    gemm_bt<0><<<32 * 48, 256, 0, stream>>>(h, wqkvT, qkv, nullptr, nullptr, nullptr, flagp, NTOK, 3072, 1024);
    qk_rope3<<<1024, 256, 0, stream>>>(qkv, rtab, q_rb, k_rb);
    attn_mfma<<<BT * NH * (SEQ / 128), 512, 0, stream>>>(q_rb, k_rb, qkv, attnb);
    gemm_bt<0><<<32 * 16, 256, 0, stream>>>(attnb, woutT, ao, nullptr, nullptr, nullptr, flagp, NTOK, 1024, 1024);
    // gate GEMM fused with combine: x1 = x + ao * sigmoid(ao@Wg + bg)
    gemm_bt<2><<<32 * 16, 256, 0, stream>>>(ao, wgateT, x1, b_gate, ao, x, flagp, NTOK, 1024, 1024);
    rmsnorm2<<<NTOK, 256, 0, stream>>>(x1, h, nullptr);
    gemm_glu<<<32 * 64, 256, 0, stream>>>(h, wmgT, act, b_mlp_g, flagp);
    gemm_bt<1><<<32 * 16, 256, 0, stream>>>(act, wmoT, (void*)out, b_mlp_o, x1, nullptr, flagp, NTOK, 1024, 4096);
}

// Round 12
// 540.669 us; speedup vs baseline: 1.0552x; 1.0014x over previous
//
#include <hip/hip_runtime.h>
#include <hip/hip_bf16.h>
#include <math.h>

#define BT 2
#define SEQ 2048
#define DIM 1024
#define NH 16
#define HD 64
#define NTOK (BT*SEQ)          // 4096

typedef __attribute__((ext_vector_type(4))) float floatx4;
typedef __attribute__((ext_vector_type(8))) short shortx8;   // 8 bf16 = 4 VGPRs (MFMA frag)
typedef __attribute__((ext_vector_type(4))) short shortx4;

// async global->LDS, 16B per lane; dest is wave-uniform base + lane*16
#define GLL16(gp, lp) __builtin_amdgcn_global_load_lds( \
    (const __attribute__((address_space(1))) unsigned int*)(const void*)(gp), \
    (__attribute__((address_space(3))) unsigned int*)(void*)(lp), 16, 0, 0)

__device__ __forceinline__ float bf2f(unsigned short u) {
    unsigned int x = ((unsigned int)u) << 16;
    return __builtin_bit_cast(float, x);
}
__device__ __forceinline__ unsigned short f2bf(float f) {
    unsigned int x = __builtin_bit_cast(unsigned int, f);
    unsigned int lsb = (x >> 16) & 1u;
    x += 0x7fffu + lsb;
    return (unsigned short)(x >> 16);
}
// dual-dtype input read: isbf=1 -> bf16, else fp32 (validated: inputs are fp32)
__device__ __forceinline__ float ldin_f(const void* p, size_t i, int isbf) {
    return isbf ? bf2f(((const unsigned short*)p)[i]) : ((const float*)p)[i];
}

// ---------------- input dtype detection (validated R1->R2) ----------------
__global__ void detect_kernel(const unsigned short* __restrict__ x, int* __restrict__ flag) {
    __shared__ int cnt;
    if (threadIdx.x == 0) cnt = 0;
    __syncthreads();
    unsigned short u = x[(size_t)threadIdx.x * 2];
    int e = (u >> 7) & 0xFF;
    if (e >= 100 && e <= 140) atomicAdd(&cnt, 1);
    __syncthreads();
    if (threadIdx.x == 0) *flag = (cnt >= 192) ? 1 : 0;
}

// ---------------- transpose (any float dtype -> bf16) ----------------
__global__ void transpose_any(const void* __restrict__ in,
                              unsigned short* __restrict__ out, int R, int C,
                              const int* __restrict__ flagp) {
    int isbf = *flagp;
    __shared__ unsigned short tile[32][33];
    int c0 = blockIdx.x * 32, r0 = blockIdx.y * 32;
    int tx = threadIdx.x, ty = threadIdx.y;
#pragma unroll
    for (int i = 0; i < 4; i++) {
        size_t idx = (size_t)(r0 + ty + i * 8) * C + c0 + tx;
        tile[ty + i * 8][tx] = isbf ? ((const unsigned short*)in)[idx]
                                    : f2bf(((const float*)in)[idx]);
    }
    __syncthreads();
#pragma unroll
    for (int i = 0; i < 4; i++)
        out[(size_t)(c0 + ty + i * 8) * R + r0 + tx] = tile[tx][ty + i * 8];
}

// ---------------- Householder Q (64x64 fp32), register-resident columns ----------
__global__ __launch_bounds__(64) void householder_kernel(const void* __restrict__ vs,
                                                         float* __restrict__ Qg,
                                                         const int* __restrict__ flagp) {
    int isbf = *flagp;
    __shared__ float vsh[64];
    int j = threadIdx.x;
    float Qc[64];
#pragma unroll
    for (int i = 0; i < 64; i++) Qc[i] = (i == j) ? 1.f : 0.f;
    for (int r = 0; r < 32; r++) {
        vsh[j] = ldin_f(vs, r * 64 + j, isbf);
        __syncthreads();
        float va[64];
#pragma unroll
        for (int i = 0; i < 64; i++) va[i] = vsh[i];
        float vn0 = 0.f, vn1 = 0.f, vn2 = 0.f, vn3 = 0.f;
        float t0 = 0.f, t1 = 0.f, t2 = 0.f, t3 = 0.f;
#pragma unroll
        for (int i = 0; i < 16; i++) {
            vn0 += va[4 * i + 0] * va[4 * i + 0];
            vn1 += va[4 * i + 1] * va[4 * i + 1];
            vn2 += va[4 * i + 2] * va[4 * i + 2];
            vn3 += va[4 * i + 3] * va[4 * i + 3];
            t0 += va[4 * i + 0] * Qc[4 * i + 0];
            t1 += va[4 * i + 1] * Qc[4 * i + 1];
            t2 += va[4 * i + 2] * Qc[4 * i + 2];
            t3 += va[4 * i + 3] * Qc[4 * i + 3];
        }
        float vn = (vn0 + vn1) + (vn2 + vn3) + 1e-8f;
        float t = (t0 + t1) + (t2 + t3);
        float c = (2.f / vn) * t;
#pragma unroll
        for (int i = 0; i < 64; i++) Qc[i] -= c * va[i];
        __syncthreads();
    }
#pragma unroll
    for (int i = 0; i < 64; i++) Qg[i * 64 + j] = Qc[i];
}

// ---------------- pre-rotate q,k head-blocks of wqkvT by Q: W'[hb] = Q @ W[hb] ----
__global__ __launch_bounds__(256) void rotate_wqkv(unsigned short* __restrict__ wT,
                                                   const float* __restrict__ Qg) {
    __shared__ float Qs[64][64];
    __shared__ unsigned short tile[64][128];
    int bid = blockIdx.x;
    int row0 = (bid >> 3) * 64;      // head-block base row (0..2047)
    int col0 = (bid & 7) * 128;      // column chunk
    int t = threadIdx.x;
#pragma unroll
    for (int i = 0; i < 16; i++) {
        int idx = i * 256 + t;
        Qs[idx >> 6][idx & 63] = Qg[idx];
    }
#pragma unroll
    for (int i = 0; i < 8; i++) {
        int e = i * 256 + t;
        int r = e >> 5, cg = (e & 31) * 4;
        *(shortx4*)&tile[r][cg] = *(const shortx4*)&wT[(size_t)(row0 + r) * 1024 + col0 + cg];
    }
    __syncthreads();
    int ib = t >> 5;                 // 0..7
    int c = (t & 31) * 4;
    float acc[8][4];
#pragma unroll
    for (int rr = 0; rr < 8; rr++)
#pragma unroll
        for (int cx = 0; cx < 4; cx++) acc[rr][cx] = 0.f;
    for (int j = 0; j < 64; j++) {
        float t0 = bf2f(tile[j][c]);
        float t1 = bf2f(tile[j][c + 1]);
        float t2 = bf2f(tile[j][c + 2]);
        float t3 = bf2f(tile[j][c + 3]);
#pragma unroll
        for (int rr = 0; rr < 8; rr++) {
            float qv = Qs[rr * 8 + ib][j];
            acc[rr][0] += qv * t0;
            acc[rr][1] += qv * t1;
            acc[rr][2] += qv * t2;
            acc[rr][3] += qv * t3;
        }
    }
#pragma unroll
    for (int rr = 0; rr < 8; rr++) {
        int i = rr * 8 + ib;
        shortx4 o4;
#pragma unroll
        for (int cx = 0; cx < 4; cx++) o4[cx] = (short)f2bf(acc[rr][cx]);
        *(shortx4*)&wT[(size_t)(row0 + i) * 1024 + col0 + c] = o4;
    }
}

// ---------------- rope cos/sin table [2048][32] interleaved (cos,sin) ----------
__global__ void rope_table(float* __restrict__ tab) {
    int idx = blockIdx.x * 256 + threadIdx.x;    // s*32 + fi
    int s = idx >> 5, fi = idx & 31;
    float invf = __expf(-(float)fi * (9.210340371976184f / 32.f));  // 10000^(-fi/32)
    float ang = (float)s * invf;
    tab[2 * idx]     = cosf(ang);
    tab[2 * idx + 1] = sinf(ang);
}

// ---------------- rmsnorm over D=1024, wave-shfl reduction (1 barrier) ----------
__global__ __launch_bounds__(256) void rmsnorm2(const void* __restrict__ x,
                                                unsigned short* __restrict__ h,
                                                const int* __restrict__ flagp) {
    int isbf = flagp ? *flagp : 1;
    __shared__ float wred[4];
    int row = blockIdx.x, t = threadIdx.x;
    size_t base = (size_t)row * DIM;
    float v[4];
    float ss = 0.f;
#pragma unroll
    for (int i = 0; i < 4; i++) {
        v[i] = ldin_f(x, base + t + 256 * i, isbf);
        ss += v[i] * v[i];
    }
#pragma unroll
    for (int m = 1; m < 64; m <<= 1) ss += __shfl_xor(ss, m, 64);
    if ((t & 63) == 0) wred[t >> 6] = ss;
    __syncthreads();
    float tot = (wred[0] + wred[1]) + (wred[2] + wred[3]);
    float rs = rsqrtf(tot * (1.f / 1024.f) + 1e-6f);
#pragma unroll
    for (int i = 0; i < 4; i++) h[base + t + 256 * i] = f2bf(v[i] * rs);
}

// ---------------- MFMA GEMM: BK=64, swizzled LDS, dbuf 2-phase, L2 super-blocks ---
// Tile order: XCD chunk -> GMxGN super-blocks (A-strip + B-group fit 4MB L2),
// m-fast inner. Loop structure identical to R11 (verified).
// MODE: 0=bf16 store, 1=f32+resid, 2=gated combine x1=xin+resid*sigmoid(val+bias).
template<int MODE, int GM, int GN>
__global__ __launch_bounds__(256) void gemm_bt(const unsigned short* __restrict__ A,
                                               const unsigned short* __restrict__ Bt,
                                               void* __restrict__ C,
                                               const void* __restrict__ bias,
                                               const unsigned short* __restrict__ resid,
                                               const void* __restrict__ xin,
                                               const int* __restrict__ flagp,
                                               int M, int N, int K) {
    __shared__ __align__(16) unsigned short As[2][128][64];   // 32 KB
    __shared__ __align__(16) unsigned short Bs[2][64][64];    // 16 KB
    int isbf = flagp ? *flagp : 1;
    int t0 = (blockIdx.x & 7) * (gridDim.x >> 3) + (blockIdx.x >> 3);
    int nbn = N >> 6;
    constexpr int SB = GM * GN;
    int s0 = t0 / SB, inner = t0 % SB;
    int sbn = nbn / GN;
    int m0 = ((s0 / sbn) * GM + (inner % GM)) * 128;
    int n0 = ((s0 % sbn) * GN + (inner / GM)) * 64;
    int t = threadIdx.x;
    int lane = t & 63;
    int w = t >> 6;
    int wr = (w >> 1) * 64;
    int wc = (w & 1) * 32;
    int lr = lane & 15;
    int kg = lane >> 4;
    int l8 = lane >> 3, s8 = lane & 7;
    int segswz = (s8 ^ l8) * 8;              // global col offset (shorts), lane-const
    int cs0 = ((kg)     ^ (lr & 7)) * 8;     // LDS col (shorts), kk=0
    int cs1 = ((4 + kg) ^ (lr & 7)) * 8;     // kk=1

    floatx4 acc[4][2];
#pragma unroll
    for (int i = 0; i < 4; i++)
#pragma unroll
        for (int j = 0; j < 2; j++) acc[i][j] = (floatx4){0.f, 0.f, 0.f, 0.f};

    int rbase = w * 8 + l8;                  // staged row within 32-row group
    const unsigned short* aP0 = A + (size_t)(m0 + rbase +  0) * K + segswz;
    const unsigned short* aP1 = A + (size_t)(m0 + rbase + 32) * K + segswz;
    const unsigned short* aP2 = A + (size_t)(m0 + rbase + 64) * K + segswz;
    const unsigned short* aP3 = A + (size_t)(m0 + rbase + 96) * K + segswz;
    const unsigned short* bP0 = Bt + (size_t)(n0 + rbase +  0) * K + segswz;
    const unsigned short* bP1 = Bt + (size_t)(n0 + rbase + 32) * K + segswz;

    auto STAGE = [&](int s, int B) {
        int off = s * 64;
        GLL16(aP0 + off, &As[B][w * 8 +  0][0]);
        GLL16(aP1 + off, &As[B][w * 8 + 32][0]);
        GLL16(aP2 + off, &As[B][w * 8 + 64][0]);
        GLL16(aP3 + off, &As[B][w * 8 + 96][0]);
        GLL16(bP0 + off, &Bs[B][w * 8 +  0][0]);
        GLL16(bP1 + off, &Bs[B][w * 8 + 32][0]);
    };
    auto MM = [&](int B) {
        shortx8 af[4][2], bf[2][2];
#pragma unroll
        for (int i = 0; i < 4; i++) {
            af[i][0] = *(const shortx8*)&As[B][wr + i * 16 + lr][cs0];
            af[i][1] = *(const shortx8*)&As[B][wr + i * 16 + lr][cs1];
        }
#pragma unroll
        for (int j = 0; j < 2; j++) {
            bf[j][0] = *(const shortx8*)&Bs[B][wc + j * 16 + lr][cs0];
            bf[j][1] = *(const shortx8*)&Bs[B][wc + j * 16 + lr][cs1];
        }
#pragma unroll
        for (int i = 0; i < 4; i++)
#pragma unroll
            for (int j = 0; j < 2; j++) {
                acc[i][j] = __builtin_amdgcn_mfma_f32_16x16x32_bf16(af[i][0], bf[j][0], acc[i][j], 0, 0, 0);
                acc[i][j] = __builtin_amdgcn_mfma_f32_16x16x32_bf16(af[i][1], bf[j][1], acc[i][j], 0, 0, 0);
            }
    };

    int NS = K >> 6;                         // K multiple of 128 -> NS even
    STAGE(0, 0);
    __syncthreads();
    for (int s = 0; s < NS; s += 2) {
        if (s + 1 < NS) STAGE(s + 1, 1);     // prefetch hides under compute
        MM(0);
        __syncthreads();                     // vmcnt(0)+barrier: buf1 ready, buf0 free
        if (s + 1 < NS) {
            if (s + 2 < NS) STAGE(s + 2, 0);
            MM(1);
            __syncthreads();
        }
    }
#pragma unroll
    for (int i = 0; i < 4; i++) {
#pragma unroll
        for (int j = 0; j < 2; j++) {
            int col = n0 + wc + j * 16 + lr;
            int rb = m0 + wr + i * 16 + kg * 4;
            float bv = bias ? ldin_f(bias, col, isbf) : 0.f;
#pragma unroll
            for (int r = 0; r < 4; r++) {
                float val = acc[i][j][r] + bv;
                size_t oidx = (size_t)(rb + r) * N + col;
                if constexpr (MODE == 0) {
                    ((unsigned short*)C)[oidx] = f2bf(val);
                } else if constexpr (MODE == 1) {
                    ((float*)C)[oidx] = val + bf2f(resid[oidx]);
                } else {
                    float a = bf2f(resid[oidx]);               // ao
                    float sg = 1.f / (1.f + __expf(-val));
                    ((unsigned short*)C)[oidx] = f2bf(ldin_f(xin, oidx, isbf) + a * sg);
                }
            }
        }
    }
}

// ---------------- fused MLP-gate GEMM + GLU: act = val * gelu(g) ----------------
// 8x8 super-blocks (2MB A-strip + 2MB g/v B-group fit L2); loop as gemm_bt.
__global__ __launch_bounds__(256) void gemm_glu(const unsigned short* __restrict__ A,
                                                const unsigned short* __restrict__ Bt,
                                                unsigned short* __restrict__ act,
                                                const void* __restrict__ bias,
                                                const int* __restrict__ flagp) {
    __shared__ __align__(16) unsigned short As[2][128][64];   // 32 KB
    __shared__ __align__(16) unsigned short Bg[2][64][64];    // 16 KB
    __shared__ __align__(16) unsigned short Bv[2][64][64];    // 16 KB
    const int K = 1024;
    int isbf = *flagp;
    int t0 = (blockIdx.x & 7) * (gridDim.x >> 3) + (blockIdx.x >> 3);
    // 32m x 64n tiles; super-blocks 8m x 8n (L2: 2MB A + 2MB B), m-fast inner
    int s0 = t0 >> 6, inner = t0 & 63;
    int m0 = ((s0 >> 3) * 8 + (inner & 7)) * 128;
    int n0 = ((s0 & 7) * 8 + (inner >> 3)) * 64;
    int t = threadIdx.x;
    int lane = t & 63;
    int w = t >> 6;
    int wr = (w >> 1) * 64;
    int wc = (w & 1) * 32;
    int lr = lane & 15;
    int kg = lane >> 4;
    int l8 = lane >> 3, s8 = lane & 7;
    int segswz = (s8 ^ l8) * 8;
    int cs0 = ((kg)     ^ (lr & 7)) * 8;
    int cs1 = ((4 + kg) ^ (lr & 7)) * 8;

    floatx4 ag[4][2], av[4][2];
#pragma unroll
    for (int i = 0; i < 4; i++)
#pragma unroll
        for (int j = 0; j < 2; j++) {
            ag[i][j] = (floatx4){0.f, 0.f, 0.f, 0.f};
            av[i][j] = (floatx4){0.f, 0.f, 0.f, 0.f};
        }

    int rbase = w * 8 + l8;
    const unsigned short* aP0 = A + (size_t)(m0 + rbase +  0) * K + segswz;
    const unsigned short* aP1 = A + (size_t)(m0 + rbase + 32) * K + segswz;
    const unsigned short* aP2 = A + (size_t)(m0 + rbase + 64) * K + segswz;
    const unsigned short* aP3 = A + (size_t)(m0 + rbase + 96) * K + segswz;
    const unsigned short* gP0 = Bt + (size_t)(n0 + rbase +  0) * K + segswz;
    const unsigned short* gP1 = Bt + (size_t)(n0 + rbase + 32) * K + segswz;
    const unsigned short* vP0 = Bt + (size_t)(4096 + n0 + rbase +  0) * K + segswz;
    const unsigned short* vP1 = Bt + (size_t)(4096 + n0 + rbase + 32) * K + segswz;

    auto STAGE = [&](int s, int B) {
        int off = s * 64;
        GLL16(aP0 + off, &As[B][w * 8 +  0][0]);
        GLL16(aP1 + off, &As[B][w * 8 + 32][0]);
        GLL16(aP2 + off, &As[B][w * 8 + 64][0]);
        GLL16(aP3 + off, &As[B][w * 8 + 96][0]);
        GLL16(gP0 + off, &Bg[B][w * 8 +  0][0]);
        GLL16(gP1 + off, &Bg[B][w * 8 + 32][0]);
        GLL16(vP0 + off, &Bv[B][w * 8 +  0][0]);
        GLL16(vP1 + off, &Bv[B][w * 8 + 32][0]);
    };
    auto MM = [&](int B) {
        shortx8 af[4][2], gf[2][2], vf[2][2];
#pragma unroll
        for (int i = 0; i < 4; i++) {
            af[i][0] = *(const shortx8*)&As[B][wr + i * 16 + lr][cs0];
            af[i][1] = *(const shortx8*)&As[B][wr + i * 16 + lr][cs1];
        }
#pragma unroll
        for (int j = 0; j < 2; j++) {
            gf[j][0] = *(const shortx8*)&Bg[B][wc + j * 16 + lr][cs0];
            gf[j][1] = *(const shortx8*)&Bg[B][wc + j * 16 + lr][cs1];
            vf[j][0] = *(const shortx8*)&Bv[B][wc + j * 16 + lr][cs0];
            vf[j][1] = *(const shortx8*)&Bv[B][wc + j * 16 + lr][cs1];
        }
#pragma unroll
        for (int i = 0; i < 4; i++)
#pragma unroll
            for (int j = 0; j < 2; j++) {
                ag[i][j] = __builtin_amdgcn_mfma_f32_16x16x32_bf16(af[i][0], gf[j][0], ag[i][j], 0, 0, 0);
                ag[i][j] = __builtin_amdgcn_mfma_f32_16x16x32_bf16(af[i][1], gf[j][1], ag[i][j], 0, 0, 0);
                av[i][j] = __builtin_amdgcn_mfma_f32_16x16x32_bf16(af[i][0], vf[j][0], av[i][j], 0, 0, 0);
                av[i][j] = __builtin_amdgcn_mfma_f32_16x16x32_bf16(af[i][1], vf[j][1], av[i][j], 0, 0, 0);
            }
    };

    const int NS = K >> 6;                   // 16
    STAGE(0, 0);
    __syncthreads();
    for (int s = 0; s < NS; s += 2) {
        if (s + 1 < NS) STAGE(s + 1, 1);
        MM(0);
        __syncthreads();
        if (s + 1 < NS) {
            if (s + 2 < NS) STAGE(s + 2, 0);
            MM(1);
            __syncthreads();
        }
    }
#pragma unroll
    for (int i = 0; i < 4; i++) {
#pragma unroll
        for (int j = 0; j < 2; j++) {
            int col = n0 + wc + j * 16 + lr;
            int rb = m0 + wr + i * 16 + kg * 4;
            float bgv = ldin_f(bias, col, isbf);
            float bvv = ldin_f(bias, 4096 + col, isbf);
#pragma unroll
            for (int r = 0; r < 4; r++) {
                float g = ag[i][j][r] + bgv;
                float v = av[i][j][r] + bvv;
                float ge = 0.5f * g * (1.f + erff(g * 0.70710678118f));
                act[(size_t)(rb + r) * 4096 + col] = f2bf(v * ge);
            }
        }
    }
}

// ---------------- RoPE + relayout to head-major (Householder folded/cancelled) ----
__global__ __launch_bounds__(256) void qk_rope3(const unsigned short* __restrict__ qkv,
                                                const float* __restrict__ tab,
                                                unsigned short* __restrict__ q_r,
                                                unsigned short* __restrict__ k_r) {
    int tid = blockIdx.x * 256 + threadIdx.x;    // = ts*64 + h*4 + c
    int c = tid & 3;
    int h = (tid >> 2) & 15;
    int ts = tid >> 6;
    int s = ts & 2047, b = ts >> 11;
    int d0 = c * 8;
    const unsigned short* base = qkv + (size_t)ts * 3072 + h * 64;
    shortx8 qlo = *(const shortx8*)(base + d0);
    shortx8 qhi = *(const shortx8*)(base + d0 + 32);
    shortx8 klo = *(const shortx8*)(base + 1024 + d0);
    shortx8 khi = *(const shortx8*)(base + 1024 + d0 + 32);
    const float* tp = tab + (size_t)s * 64 + d0 * 2;   // (cos,sin) pairs, fi = d0..d0+7
    shortx8 oql, oqh, okl, okh;
#pragma unroll
    for (int i = 0; i < 8; i++) {
        float cv = tp[2 * i], sv = tp[2 * i + 1];
        float ql = bf2f((unsigned short)qlo[i]), qh = bf2f((unsigned short)qhi[i]);
        float kl = bf2f((unsigned short)klo[i]), kh = bf2f((unsigned short)khi[i]);
        oql[i] = (short)f2bf(ql * cv - qh * sv);
        oqh[i] = (short)f2bf(qh * cv + ql * sv);
        okl[i] = (short)f2bf(kl * cv - kh * sv);
        okh[i] = (short)f2bf(kh * cv + kl * sv);
    }
    size_t o = ((size_t)(b * NH + h) * SEQ + s) * HD + d0;
    *(shortx8*)(q_r + o)      = oql;
    *(shortx8*)(q_r + o + 32) = oqh;
    *(shortx8*)(k_r + o)      = okl;
    *(shortx8*)(k_r + o + 32) = okh;
}

// ---------------- MFMA flash attention (block-causal): swapped QK^T + setprio ----
__global__ __launch_bounds__(512) void attn_mfma(const unsigned short* __restrict__ q_r,
                                                 const unsigned short* __restrict__ k_r,
                                                 const unsigned short* __restrict__ qkv,
                                                 unsigned short* __restrict__ attn) {
    __shared__ __align__(16) unsigned short Ks[64][72];      // [key][dim], +8 pad
    __shared__ __align__(16) unsigned short Vt[64 * 72];     // [dim][72], 8-key blocks XOR-swizzled
    __shared__ __align__(16) unsigned short Ps[8][16][72];   // per-wave P [qrow][key]
    int bid = blockIdx.x;
    int qblk = 15 - (bid & 15);                  // big q-blocks first
    int bh = bid >> 4;
    int b = bh >> 4, h = bh & 15;
    size_t bh_off = (size_t)bh * SEQ * HD;
    int tid = threadIdx.x;
    int wv = tid >> 6, lane = tid & 63;
    int l16 = lane & 15, quad = lane >> 4;
    int q0 = qblk * 128 + wv * 16;

    const unsigned short* qrow = q_r + bh_off + (size_t)(q0 + l16) * HD + quad * 8;
    shortx8 aq0 = *(const shortx8*)(qrow);
    shortx8 aq1 = *(const shortx8*)(qrow + 32);

    floatx4 o[4];
#pragma unroll
    for (int nt = 0; nt < 4; nt++) o[nt] = (floatx4){0.f, 0.f, 0.f, 0.f};
    float m_run = -1e30f, l_run = 0.f;           // this lane owns q-row q0+l16

    int nk = (qblk + 1) * 128;
    int skey = tid >> 3;              // 0..63
    int sd0 = (tid & 7) * 8;          // dim offset
    const unsigned short* kbase = k_r + bh_off + (size_t)skey * HD + sd0;
    const unsigned short* vbase = qkv + ((size_t)(b * SEQ + skey)) * 3072 + 2048 + h * 64 + sd0;
    int vco = (((skey >> 3) ^ (tid & 7)) * 8) + (skey & 7);

    shortx8 kv = *(const shortx8*)kbase;          // prefetch tile 0
    shortx8 vvv = *(const shortx8*)vbase;

    for (int k0 = 0; k0 < nk; k0 += 64) {
        __syncthreads();                          // prev tile's LDS reads done
        *(shortx8*)&Ks[skey][sd0] = kv;
#pragma unroll
        for (int i = 0; i < 8; i++) Vt[(size_t)(sd0 + i) * 72 + vco] = (unsigned short)vvv[i];
        __syncthreads();                          // staged tile visible
        if (k0 + 64 < nk) {                       // prefetch next tile (hidden under compute)
            kv  = *(const shortx8*)(kbase + (size_t)(k0 + 64) * HD);
            vvv = *(const shortx8*)(vbase + (size_t)(k0 + 64) * 3072);
        }

        // swapped QK^T: D[key][q], col=l16=q-row, row=quad*4+r=key (within kt*16)
        floatx4 sc[4];
        __builtin_amdgcn_s_setprio(1);
#pragma unroll
        for (int kt = 0; kt < 4; kt++) {
            shortx8 bk0 = *(const shortx8*)&Ks[kt * 16 + l16][quad * 8];
            shortx8 bk1 = *(const shortx8*)&Ks[kt * 16 + l16][32 + quad * 8];
            floatx4 z = (floatx4){0.f, 0.f, 0.f, 0.f};
            z = __builtin_amdgcn_mfma_f32_16x16x32_bf16(bk0, aq0, z, 0, 0, 0);
            z = __builtin_amdgcn_mfma_f32_16x16x32_bf16(bk1, aq1, z, 0, 0, 0);
            sc[kt] = z;
        }
        __builtin_amdgcn_s_setprio(0);
        // lane holds 16 scores (keys kt*16+quad*4+r) for q-row l16
        float sv[16], mx[16];
#pragma unroll
        for (int kt = 0; kt < 4; kt++)
#pragma unroll
            for (int r = 0; r < 4; r++) sv[kt * 4 + r] = sc[kt][r] * 0.125f;
#pragma unroll
        for (int i = 0; i < 16; i++) mx[i] = sv[i];
#pragma unroll
        for (int st = 8; st > 0; st >>= 1)
#pragma unroll
            for (int i = 0; i < 8; i++)
                if (i < st) mx[i] = fmaxf(mx[i], mx[i + st]);
        float mt = mx[0];
        mt = fmaxf(mt, __shfl_xor(mt, 16, 64));   // reduce over 4 quads
        mt = fmaxf(mt, __shfl_xor(mt, 32, 64));
        float nm = fmaxf(m_run, mt);
        float al = __expf(m_run - nm);
        m_run = nm;
        float p[16];
#pragma unroll
        for (int i = 0; i < 16; i++) p[i] = __expf(sv[i] - nm);
        float sm[8];
#pragma unroll
        for (int i = 0; i < 8; i++) sm[i] = p[i] + p[i + 8];
        float ps = ((sm[0] + sm[1]) + (sm[2] + sm[3])) + ((sm[4] + sm[5]) + (sm[6] + sm[7]));
        ps += __shfl_xor(ps, 16, 64);
        ps += __shfl_xor(ps, 32, 64);
        l_run = l_run * al + ps;
        // P -> LDS as aligned b64 (keys kt*16+quad*4 .. +3 contiguous)
#pragma unroll
        for (int kt = 0; kt < 4; kt++) {
            shortx4 pk;
#pragma unroll
            for (int r = 0; r < 4; r++) pk[r] = (short)f2bf(p[kt * 4 + r]);
            *(shortx4*)&Ps[wv][l16][kt * 16 + quad * 4] = pk;
        }
        // rescale o: o-row quad*4+r needs al from lane l16=quad*4+r
#pragma unroll
        for (int r = 0; r < 4; r++) {
            float alr = __shfl(al, quad * 4 + r, 64);
            o[0][r] *= alr; o[1][r] *= alr; o[2][r] *= alr; o[3][r] *= alr;
        }
        // PV (wave-private Ps RAW: in-order, no barrier)
        __builtin_amdgcn_s_setprio(1);
#pragma unroll
        for (int h2 = 0; h2 < 2; h2++) {
            shortx8 ap = *(const shortx8*)&Ps[wv][l16][h2 * 32 + quad * 8];
#pragma unroll
            for (int nt = 0; nt < 4; nt++) {
                int dd = nt * 16 + l16;
                shortx8 bvv = *(const shortx8*)&Vt[(size_t)dd * 72 +
                                                   (((h2 * 4 + quad) ^ ((dd >> 3) & 7)) * 8)];
                o[nt] = __builtin_amdgcn_mfma_f32_16x16x32_bf16(ap, bvv, o[nt], 0, 0, 0);
            }
        }
        __builtin_amdgcn_s_setprio(0);
    }
#pragma unroll
    for (int r = 0; r < 4; r++) {
        float lv = __shfl(l_run, quad * 4 + r, 64);
        float inv_l = 1.f / lv;
        int s = q0 + quad * 4 + r;
        unsigned short* op = attn + ((size_t)(b * SEQ + s)) * DIM + h * 64;
#pragma unroll
        for (int nt = 0; nt < 4; nt++) op[nt * 16 + l16] = f2bf(o[nt][r] * inv_l);
    }
}

extern "C" void kernel_launch(void* const* d_in, const int* in_sizes, int n_in,
                              void* d_out, int out_size, void* d_ws, size_t ws_size,
                              hipStream_t stream) {
    const unsigned short* x        = (const unsigned short*)d_in[0];
    const void* vs       = d_in[3];
    const void* w_qkv    = d_in[4];
    const void* w_out    = d_in[5];
    const void* w_gate   = d_in[6];
    const void* b_gate   = d_in[7];
    const void* w_mlp_g  = d_in[8];
    const void* b_mlp_g  = d_in[9];
    const void* w_mlp_o  = d_in[10];
    const void* b_mlp_o  = d_in[11];
    float* out = (float*)d_out;    // reference output dtype is float32
    char* ws = (char*)d_ws;

    if (n_in < 12) return;
    if (in_sizes[0] != 4194304 || in_sizes[3] != 2048 || in_sizes[4] != 3145728 ||
        in_sizes[8] != 8388608 || in_sizes[10] != 4194304 || in_sizes[7] != 1024) return;

    const size_t o_T   = 0;            // transposed weights, 35,651,584
    const size_t o_Qg  = 35651584;     // Qg 16 KiB + flag (32 KiB reserved)
    const size_t o_h   = 35684352;     // 8,388,608
    const size_t o_B   = 44072960;     // 25,165,824: qkv (live through attn) | ao after attn
    const size_t o_C   = 69238784;     // q_rb,k_rb,attnb | x1, act after attn
    const size_t o_gv  = 94404608;     // rope table (512 KiB) early
    const size_t total = 161513472;
    if (ws_size < total) return;

    unsigned short* wqkvT  = (unsigned short*)(ws + o_T);             // [3072,1024]
    unsigned short* woutT  = (unsigned short*)(ws + o_T + 6291456);   // [1024,1024]
    unsigned short* wgateT = (unsigned short*)(ws + o_T + 8388608);   // [1024,1024]
    unsigned short* wmgT   = (unsigned short*)(ws + o_T + 10485760);  // [8192,1024]
    unsigned short* wmoT   = (unsigned short*)(ws + o_T + 27262976);  // [1024,4096]
    float*          Qg     = (float*)(ws + o_Qg);
    int*            flagp  = (int*)(ws + o_Qg + 16384);
    unsigned short* h      = (unsigned short*)(ws + o_h);
    unsigned short* qkv    = (unsigned short*)(ws + o_B);             // 24 MiB, live until attn done
    unsigned short* ao     = (unsigned short*)(ws + o_B + 8388608);   // written after attn
    unsigned short* q_rb   = (unsigned short*)(ws + o_C);
    unsigned short* k_rb   = (unsigned short*)(ws + o_C + 8388608);
    unsigned short* attnb  = (unsigned short*)(ws + o_C + 16777216);
    unsigned short* x1     = (unsigned short*)(ws + o_C);             // after attn done
    unsigned short* act    = (unsigned short*)(ws + o_C + 8388608);   // 32 MiB, after attn done
    float*          rtab   = (float*)(ws + o_gv);                     // read only pre-attn

    detect_kernel<<<1, 256, 0, stream>>>(x, flagp);
    householder_kernel<<<1, 64, 0, stream>>>(vs, Qg, flagp);
    rope_table<<<256, 256, 0, stream>>>(rtab);

    dim3 tb(32, 8);
    transpose_any<<<dim3(3072 / 32, 1024 / 32), tb, 0, stream>>>(w_qkv,   wqkvT, 1024, 3072, flagp);
    transpose_any<<<dim3(1024 / 32, 1024 / 32), tb, 0, stream>>>(w_out,   woutT, 1024, 1024, flagp);
    transpose_any<<<dim3(1024 / 32, 1024 / 32), tb, 0, stream>>>(w_gate,  wgateT, 1024, 1024, flagp);
    transpose_any<<<dim3(8192 / 32, 1024 / 32), tb, 0, stream>>>(w_mlp_g, wmgT, 1024, 8192, flagp);
    transpose_any<<<dim3(1024 / 32, 4096 / 32), tb, 0, stream>>>(w_mlp_o, wmoT, 4096, 1024, flagp);
    rotate_wqkv<<<256, 256, 0, stream>>>(wqkvT, Qg);   // fold q = (h Wq) Q^T into weights

    rmsnorm2<<<NTOK, 256, 0, stream>>>(x, h, flagp);
    gemm_bt<0, 4, 8><<<32 * 48, 256, 0, stream>>>(h, wqkvT, qkv, nullptr, nullptr, nullptr, flagp, NTOK, 3072, 1024);
    qk_rope3<<<1024, 256, 0, stream>>>(qkv, rtab, q_rb, k_rb);
    attn_mfma<<<BT * NH * (SEQ / 128), 512, 0, stream>>>(q_rb, k_rb, qkv, attnb);
    gemm_bt<0, 4, 8><<<32 * 16, 256, 0, stream>>>(attnb, woutT, ao, nullptr, nullptr, nullptr, flagp, NTOK, 1024, 1024);
    // gate GEMM fused with combine: x1 = x + ao * sigmoid(ao@Wg + bg)
    gemm_bt<2, 4, 8><<<32 * 16, 256, 0, stream>>>(ao, wgateT, x1, b_gate, ao, x, flagp, NTOK, 1024, 1024);
    rmsnorm2<<<NTOK, 256, 0, stream>>>(x1, h, nullptr);
    gemm_glu<<<32 * 64, 256, 0, stream>>>(h, wmgT, act, b_mlp_g, flagp);
    gemm_bt<1, 2, 4><<<32 * 16, 256, 0, stream>>>(act, wmoT, (void*)out, b_mlp_o, x1, nullptr, flagp, NTOK, 1024, 4096);
}